// Round 7
// baseline (598.192 us; speedup 1.0000x reference)
//
#include <hip/hip_runtime.h>
#include <math.h>

// Problem constants (B=8, L=4096, D=512, H=8, top_k = int(log(4096)) = 8)
#define NB 8
#define NL 4096
#define ND 512
#define NK 8

typedef unsigned short ushort_t;
typedef __bf16 bf16x8 __attribute__((ext_vector_type(8)));
typedef float f32x4 __attribute__((ext_vector_type(4)));

__device__ __forceinline__ unsigned short f2bf(float x) {
    unsigned u = __builtin_bit_cast(unsigned, x);
    u += 0x7fff + ((u >> 16) & 1);   // round-to-nearest-even
    return (unsigned short)(u >> 16);
}
__device__ __forceinline__ float bf2f(unsigned short b) {
    unsigned u = ((unsigned)b) << 16;
    return __builtin_bit_cast(float, u);
}

// ---------------------------------------------------------------------------
// Small GEMM: C[i,j] = sum_{k<512} A[k*sa_k + i*sa_i] * B[k*sb_k + j*sb_j]
// ---------------------------------------------------------------------------
__global__ void k_smallgemm(const float* __restrict__ A, const float* __restrict__ Bm,
                            float* __restrict__ C, int sa_k, int sa_i, int sb_k, int sb_j) {
    int i = blockIdx.y * 16 + threadIdx.y;
    int j = blockIdx.x * 16 + threadIdx.x;
    float acc = 0.f;
    for (int k = 0; k < ND; ++k)
        acc += A[k * sa_k + i * sa_i] * Bm[k * sb_k + j * sb_j];
    C[i * ND + j] = acc;
}

// bp[i] = bo[i] + sum_k Wo[i,k]*bv[k]
__global__ void k_biasprep(const float* __restrict__ Wo, const float* __restrict__ bv,
                           const float* __restrict__ bo, float* __restrict__ bp) {
    int i = blockIdx.x * blockDim.x + threadIdx.x;
    float acc = bo[i];
    for (int k = 0; k < ND; ++k) acc += Wo[i * ND + k] * bv[k];
    bp[i] = acc;
}

// Split fp32 rows into [row][0:512]=hi bf16, [row][512:1024]=lo bf16.
// grid = rows/2 blocks of 256 threads (each thread: 4 elements).
__global__ __launch_bounds__(256) void k_split(const float* __restrict__ src,
                                               ushort_t* __restrict__ dst) {
    int gid = blockIdx.x * 256 + threadIdx.x;
    int row = gid >> 7;
    int kc = (gid & 127) * 4;
    float4 v = *(const float4*)(src + (size_t)row * ND + kc);
    ushort4 hi, lo;
    hi.x = f2bf(v.x); lo.x = f2bf(v.x - bf2f(hi.x));
    hi.y = f2bf(v.y); lo.y = f2bf(v.y - bf2f(hi.y));
    hi.z = f2bf(v.z); lo.z = f2bf(v.z - bf2f(hi.z));
    hi.w = f2bf(v.w); lo.w = f2bf(v.w - bf2f(hi.w));
    *(ushort4*)(dst + (size_t)row * 1024 + kc) = hi;
    *(ushort4*)(dst + (size_t)row * 1024 + 512 + kc) = lo;
}

// ---------------------------------------------------------------------------
// Transpose X[b,l,c] -> XT[b,c,l]   (32x32 LDS tiles)
// ---------------------------------------------------------------------------
__global__ __launch_bounds__(256) void k_transpose(const float* __restrict__ X,
                                                   float* __restrict__ XT) {
    __shared__ float t[32][33];
    int b  = blockIdx.z;
    int l0 = blockIdx.x * 32;
    int c0 = blockIdx.y * 32;
    const float* Xb = X + (size_t)b * NL * ND;
    float* XTb = XT + (size_t)b * ND * NL;
    int tx = threadIdx.x, ty = threadIdx.y;  // 32 x 8
#pragma unroll
    for (int j = 0; j < 4; ++j)
        t[ty + j * 8][tx] = Xb[(size_t)(l0 + ty + j * 8) * ND + c0 + tx];
    __syncthreads();
#pragma unroll
    for (int j = 0; j < 4; ++j)
        XTb[(size_t)(c0 + ty + j * 8) * NL + l0 + tx] = t[tx][ty + j * 8];
}

// ---------------------------------------------------------------------------
// Split-bf16 MFMA GEMM:  C[r,n] = sum_k A[r,k] * Brow[n,k]
// A, B both pre-split bf16 [rows][1024] = hi(512) | lo(512).
// R6: counted-vmcnt K-loop (T4). R1/R3/R4 were all ~97-106us regardless of
// staged bytes / conflicts / tile size -> the per-iteration vmcnt(0) drain
// (__syncthreads) was the structural ~70% stall (m233). New schedule:
// 2-deep prefetch; per iter: s_waitcnt vmcnt(8) (tile t landed, tile t+1's
// 8 loads stay in flight) + raw s_barrier -> COMPUTE -> lgkmcnt(0) +
// s_barrier -> STAGE(t+2). Never drains vmcnt to 0 in the main loop.
// setprio(1) around MFMA cluster (T5). sched_barrier(0) fences (rule #18).
// 256x256 tile, 8 waves (2M x 4N), BK=32, 128KB LDS, 1 block/CU, grid=256.
// Fragment-order LDS layout (R3): chunk q holds (row=(q>>6)*16+(q&15),
// kchunk=(q>>4)&3) so fragment ds_read_b128 is lane l -> base + l*16B.
// 3-term split: Ah*Bh + Ah*Bl + Al*Bh.
// XCD-chunked tile remap keeps A/B panels L2-resident per XCD.
// EPI=0: write transposed YT[b,n,l]; EPI=1: bias + plain [r,n].
// ---------------------------------------------------------------------------
template <int EPI>
__global__ __launch_bounds__(512, 2) void k_gemm_split(const ushort_t* __restrict__ As,
                                                       const ushort_t* __restrict__ Bs,
                                                       const float* __restrict__ bp,
                                                       float* __restrict__ Out) {
    struct Buf { ushort_t ahi[256 * 32]; ushort_t alo[256 * 32];
                 ushort_t bhi[256 * 32]; ushort_t blo[256 * 32]; };   // 64 KB
    __shared__ union USm {
        Buf s[2];                                                      // 128 KB
        float t[32 * 257];                                             // epilogue transpose
    } sm;
    const int tid = threadIdx.x;
    // hw linear block id -> XCD-chunked bijection (256 = 8 XCDs * 32)
    const int flat = blockIdx.x + (blockIdx.y << 7);   // gridDim.x = 128
    const int wswz = ((flat & 7) << 5) + (flat >> 3);
    const int l0 = (wswz >> 1) * 256;   // 128 l-tiles
    const int n0 = (wswz & 1) * 256;    // 2 n-tiles, adjacent per A-panel
    const int lane = tid & 63;
    const int w = tid >> 6;             // 0..7
    const int wr = (w & 1) * 128;       // wave row-group: 0 / 128
    const int wc = (w >> 1) * 64;       // wave col-group: 0/64/128/192
    const int m = lane & 15;
    const int quad = lane >> 4;

    f32x4 acc[8][4];
#pragma unroll
    for (int i = 0; i < 8; ++i)
#pragma unroll
        for (int j = 0; j < 4; ++j) acc[i][j] = (f32x4){0.f, 0.f, 0.f, 0.f};

    // Stage with fragment-order source permutation. Exactly 8 global_load_lds
    // per thread (=> vmcnt granularity of 8 per STAGE).
    // chunk q (0..1023): row = (q>>6)*16 + (q&15), kchunk = (q>>4)&3.
    // LDS dest is linear q*16B (wave-uniform base + lane*16 as HW requires).
    auto STAGE = [&](int bf, int k0) {
#pragma unroll
        for (int v = 0; v < 2; ++v) {
            int q = v * 512 + tid;
            int row = ((q >> 6) << 4) | (q & 15);
            int kc = (q >> 4) & 3;
            const ushort_t* asrc = As + (size_t)(l0 + row) * 1024 + k0 + kc * 8;
            __builtin_amdgcn_global_load_lds(
                (const __attribute__((address_space(1))) unsigned int*)asrc,
                (__attribute__((address_space(3))) unsigned int*)&sm.s[bf].ahi[q * 8], 16, 0, 0);
            __builtin_amdgcn_global_load_lds(
                (const __attribute__((address_space(1))) unsigned int*)(asrc + 512),
                (__attribute__((address_space(3))) unsigned int*)&sm.s[bf].alo[q * 8], 16, 0, 0);
            const ushort_t* bsrc = Bs + (size_t)(n0 + row) * 1024 + k0 + kc * 8;
            __builtin_amdgcn_global_load_lds(
                (const __attribute__((address_space(1))) unsigned int*)bsrc,
                (__attribute__((address_space(3))) unsigned int*)&sm.s[bf].bhi[q * 8], 16, 0, 0);
            __builtin_amdgcn_global_load_lds(
                (const __attribute__((address_space(1))) unsigned int*)(bsrc + 512),
                (__attribute__((address_space(3))) unsigned int*)&sm.s[bf].blo[q * 8], 16, 0, 0);
        }
    };

    // Fragment read: block bi = 64 chunks = 512 ushorts; lane l reads
    // bi*1KB + l*16B (linear, conflict-free). Lane gets
    // A[wr+16i+m][k0 + quad*8 .. +8].
    auto COMPUTE = [&](int bf) {
        bf16x8 ah[8], al[8];
#pragma unroll
        for (int i = 0; i < 8; ++i) {
            int off = ((wr >> 4) + i) * 512 + lane * 8;
            ah[i] = *(const bf16x8*)&sm.s[bf].ahi[off];
            al[i] = *(const bf16x8*)&sm.s[bf].alo[off];
        }
        __builtin_amdgcn_s_setprio(1);
#pragma unroll
        for (int j = 0; j < 4; ++j) {
            int off = ((wc >> 4) + j) * 512 + lane * 8;
            bf16x8 bh = *(const bf16x8*)&sm.s[bf].bhi[off];
            bf16x8 bl = *(const bf16x8*)&sm.s[bf].blo[off];
#pragma unroll
            for (int i = 0; i < 8; ++i) {
                acc[i][j] = __builtin_amdgcn_mfma_f32_16x16x32_bf16(ah[i], bh, acc[i][j], 0, 0, 0);
                acc[i][j] = __builtin_amdgcn_mfma_f32_16x16x32_bf16(ah[i], bl, acc[i][j], 0, 0, 0);
                acc[i][j] = __builtin_amdgcn_mfma_f32_16x16x32_bf16(al[i], bh, acc[i][j], 0, 0, 0);
            }
        }
        __builtin_amdgcn_s_setprio(0);
    };

    // prologue: 2-deep prefetch (16 loads/thread in flight)
    STAGE(0, 0);
    STAGE(1, 32);
    for (int t = 0; t < 15; ++t) {
        // wait for tile t's loads; tile t+1's 8 loads stay in flight
        asm volatile("s_waitcnt vmcnt(8)" ::: "memory");
        __builtin_amdgcn_sched_barrier(0);
        __builtin_amdgcn_s_barrier();      // all waves' tile-t data in LDS
        COMPUTE(t & 1);
        asm volatile("s_waitcnt lgkmcnt(0)" ::: "memory");
        __builtin_amdgcn_sched_barrier(0);
        __builtin_amdgcn_s_barrier();      // all waves done reading buf[t&1]
        __builtin_amdgcn_sched_barrier(0);
        if (t < 14) STAGE(t & 1, (t + 2) * 32);
    }
    asm volatile("s_waitcnt vmcnt(0)" ::: "memory");
    __builtin_amdgcn_sched_barrier(0);
    __builtin_amdgcn_s_barrier();
    COMPUTE(1);   // tile 15

    if (EPI == 1) {
        // bias + plain [row, col]
#pragma unroll
        for (int j = 0; j < 4; ++j) {
            int col = n0 + wc + 16 * j + m;
            float bv = bp[col];
#pragma unroll
            for (int i = 0; i < 8; ++i) {
                size_t rbase = (size_t)(l0 + wr + 16 * i + quad * 4) * ND + col;
#pragma unroll
                for (int r = 0; r < 4; ++r)
                    Out[rbase + (size_t)r * ND] = acc[i][j][r] + bv;
            }
        }
    } else {
        // transposed write YT[b, n, l] via LDS, 32-col chunks (8 chunks)
#pragma unroll
        for (int c = 0; c < 8; ++c) {
            __syncthreads();
            if ((wc >> 6) == (c >> 1)) {
                int jb = (c & 1) * 2;
#pragma unroll
                for (int jj = 0; jj < 2; ++jj) {
                    int j = jb + jj;
                    int cl = 16 * jj + m;
#pragma unroll
                    for (int i = 0; i < 8; ++i)
#pragma unroll
                        for (int r = 0; r < 4; ++r)
                            sm.t[cl * 257 + wr + 16 * i + quad * 4 + r] = acc[i][j][r];
                }
            }
            __syncthreads();
#pragma unroll
            for (int it = 0; it < 16; ++it) {
                int idx = it * 512 + tid;
                int cl = idx >> 8;
                int row = idx & 255;
                int rg = l0 + row;
                Out[((size_t)((rg >> 12) * ND + n0 + c * 32 + cl)) * NL + (rg & 4095)] =
                    sm.t[cl * 257 + row];
            }
        }
    }
}

// ---------------------------------------------------------------------------
// 16-point in-register DFT (natural in/out). DIR=+1 fwd (e^{-i}), -1 inverse.
// ---------------------------------------------------------------------------
template <int DIR>
__device__ __forceinline__ void fft16(float2* v) {
    const float ct[8] = {1.f, 0.923879533f, 0.707106781f, 0.382683432f,
                         0.f, -0.382683432f, -0.707106781f, -0.923879533f};
    const float st[8] = {0.f, 0.382683432f, 0.707106781f, 0.923879533f,
                         1.f, 0.923879533f, 0.707106781f, 0.382683432f};
    const int br[16] = {0, 8, 4, 12, 2, 10, 6, 14, 1, 9, 5, 13, 3, 11, 7, 15};
    float2 a[16];
#pragma unroll
    for (int i = 0; i < 16; ++i) a[i] = v[br[i]];
#pragma unroll
    for (int s = 1; s <= 4; ++s) {
        const int L = 1 << s, h = L >> 1;
#pragma unroll
        for (int g = 0; g < 16; g += L)
#pragma unroll
            for (int p = 0; p < h; ++p) {
                int k = p << (4 - s);
                float wr = ct[k];
                float wi = (DIR > 0) ? -st[k] : st[k];
                int i1 = g + p, i2 = i1 + h;
                float tr = wr * a[i2].x - wi * a[i2].y;
                float ti = wr * a[i2].y + wi * a[i2].x;
                a[i2].x = a[i1].x - tr; a[i2].y = a[i1].y - ti;
                a[i1].x += tr;          a[i1].y += ti;
            }
    }
#pragma unroll
    for (int i = 0; i < 16; ++i) v[i] = a[i];
}

__device__ __forceinline__ float2 cmul(float2 a, float2 b) {
    return make_float2(a.x * b.x - a.y * b.y, a.x * b.y + a.y * b.x);
}
#define PADI(i) ((i) + ((i) >> 4))

// ---------------------------------------------------------------------------
// Forward: per (batch, group of 8 channels): z = x + i*y, 4096-pt Stockham
// radix-16 FFT (3 stages), accumulate cross-spectrum
// X_c(f)*conj(Y_c(f)) = Im(Z_f*Z_{-f})/2 + i*(|Z_f|^2-|Z_{-f}|^2)/4
// into partial[b, g, f].
// ---------------------------------------------------------------------------
__global__ __launch_bounds__(256) void k_fft_fwd(const float* __restrict__ XT,
                                                 const float* __restrict__ YT,
                                                 float2* __restrict__ partial) {
    __shared__ float2 data[4352];   // 4096 + pad
    const int t = threadIdx.x;
    const int b = blockIdx.x >> 6;
    const int g = blockIdx.x & 63;

    float sv, cv;
    sincosf(-6.283185307179586f * (float)(t & 15) / 256.0f, &sv, &cv);
    const float2 w2 = make_float2(cv, sv);
    sincosf(-6.283185307179586f * (float)t / 4096.0f, &sv, &cv);
    const float2 w3 = make_float2(cv, sv);

    float2 acc[16];
#pragma unroll
    for (int r = 0; r < 16; ++r) acc[r] = make_float2(0.f, 0.f);

    for (int ch = 0; ch < 8; ++ch) {
        int c = g * 8 + ch;
        const float* xr = XT + ((size_t)b * ND + c) * NL;
        const float* yr = YT + ((size_t)b * ND + c) * NL;
        float2 v[16];
        // stage 1 (Ns=1): read natural, fft16, write idx 16t+m
#pragma unroll
        for (int mm = 0; mm < 16; ++mm)
            v[mm] = make_float2(xr[t + 256 * mm], yr[t + 256 * mm]);
        fft16<1>(v);
        __syncthreads();   // prior channel's pair-reads done
#pragma unroll
        for (int mm = 0; mm < 16; ++mm) data[PADI(16 * t + mm)] = v[mm];
        __syncthreads();
        // stage 2 (Ns=16)
#pragma unroll
        for (int mm = 0; mm < 16; ++mm) v[mm] = data[PADI(t + 256 * mm)];
        {
            float2 wm = make_float2(1.f, 0.f);
#pragma unroll
            for (int mm = 1; mm < 16; ++mm) { wm = cmul(wm, w2); v[mm] = cmul(v[mm], wm); }
        }
        fft16<1>(v);
        __syncthreads();
        {
            int base = (t >> 4) * 256 + (t & 15);
#pragma unroll
            for (int mm = 0; mm < 16; ++mm) data[PADI(base + 16 * mm)] = v[mm];
        }
        __syncthreads();
        // stage 3 (Ns=256) -> natural-order Z in registers
#pragma unroll
        for (int mm = 0; mm < 16; ++mm) v[mm] = data[PADI(t + 256 * mm)];
        {
            float2 wm = make_float2(1.f, 0.f);
#pragma unroll
            for (int mm = 1; mm < 16; ++mm) { wm = cmul(wm, w3); v[mm] = cmul(v[mm], wm); }
        }
        fft16<1>(v);
        __syncthreads();
#pragma unroll
        for (int mm = 0; mm < 16; ++mm) data[PADI(t + 256 * mm)] = v[mm];
        __syncthreads();
        // cross-spectrum accumulate
#pragma unroll
        for (int mm = 0; mm < 16; ++mm) {
            int f = t + 256 * mm;
            float2 A = v[mm];
            float2 Bz = data[PADI((4096 - f) & 4095)];
            acc[mm].x += 0.5f * (A.x * Bz.y + A.y * Bz.x);
            acc[mm].y += 0.25f * ((A.x * A.x + A.y * A.y) - (Bz.x * Bz.x + Bz.y * Bz.y));
        }
    }
    float2* out = partial + ((size_t)b * 64 + g) * 4096;
#pragma unroll
    for (int mm = 0; mm < 16; ++mm) out[256 * mm + t] = acc[mm];
}

// Reduce 64 partials -> Cf[b][f]
__global__ __launch_bounds__(256) void k_reduce(const float2* __restrict__ partial,
                                                float2* __restrict__ Cf) {
    int b = blockIdx.x >> 4;
    int f = (blockIdx.x & 15) * 256 + threadIdx.x;
    float2 s = make_float2(0.f, 0.f);
    for (int g = 0; g < 64; ++g) {
        float2 v = partial[((size_t)(b * 64 + g)) * 4096 + f];
        s.x += v.x; s.y += v.y;
    }
    Cf[(size_t)b * 4096 + f] = s;
}

// Inverse 4096-pt Stockham on Cf -> mean_corr (real part, scaled)
__global__ __launch_bounds__(256) void k_ifft(const float2* __restrict__ Cf,
                                              float* __restrict__ mc) {
    __shared__ float2 data[4352];
    const int t = threadIdx.x;
    const int b = blockIdx.x;
    float sv, cv;
    sincosf(6.283185307179586f * (float)(t & 15) / 256.0f, &sv, &cv);
    const float2 w2 = make_float2(cv, sv);
    sincosf(6.283185307179586f * (float)t / 4096.0f, &sv, &cv);
    const float2 w3 = make_float2(cv, sv);

    float2 v[16];
#pragma unroll
    for (int mm = 0; mm < 16; ++mm) v[mm] = Cf[(size_t)b * 4096 + t + 256 * mm];
    fft16<-1>(v);
#pragma unroll
    for (int mm = 0; mm < 16; ++mm) data[PADI(16 * t + mm)] = v[mm];
    __syncthreads();
#pragma unroll
    for (int mm = 0; mm < 16; ++mm) v[mm] = data[PADI(t + 256 * mm)];
    {
        float2 wm = make_float2(1.f, 0.f);
#pragma unroll
        for (int mm = 1; mm < 16; ++mm) { wm = cmul(wm, w2); v[mm] = cmul(v[mm], wm); }
    }
    fft16<-1>(v);
    __syncthreads();
    {
        int base = (t >> 4) * 256 + (t & 15);
#pragma unroll
        for (int mm = 0; mm < 16; ++mm) data[PADI(base + 16 * mm)] = v[mm];
    }
    __syncthreads();
#pragma unroll
    for (int mm = 0; mm < 16; ++mm) v[mm] = data[PADI(t + 256 * mm)];
    {
        float2 wm = make_float2(1.f, 0.f);
#pragma unroll
        for (int mm = 1; mm < 16; ++mm) { wm = cmul(wm, w3); v[mm] = cmul(v[mm], wm); }
    }
    fft16<-1>(v);
    const float scale = 1.0f / (4096.0f * 512.0f);
#pragma unroll
    for (int mm = 0; mm < 16; ++mm)
        mc[(size_t)b * NL + t + 256 * mm] = v[mm].x * scale;
}

// ---------------------------------------------------------------------------
// Top-8 + softmax per batch
// ---------------------------------------------------------------------------
__global__ __launch_bounds__(256) void k_topk(const float* __restrict__ mc,
                                              float* __restrict__ wts,
                                              int* __restrict__ dly) {
    __shared__ float vals[4096];
    __shared__ float rv[256];
    __shared__ int ri[256];
    __shared__ float tv[NK];
    __shared__ int tix[NK];
    const int tid = threadIdx.x;
    const int b = blockIdx.x;
    for (int t = tid; t < 4096; t += 256) vals[t] = mc[(size_t)b * NL + t];
    __syncthreads();
    for (int it = 0; it < NK; ++it) {
        float bv = -3.0e38f;
        int bi = 0;
        for (int t = tid; t < 4096; t += 256) {
            float v = vals[t];
            if (v > bv) { bv = v; bi = t; }
        }
        rv[tid] = bv;
        ri[tid] = bi;
        __syncthreads();
        for (int off = 128; off > 0; off >>= 1) {
            if (tid < off) {
                if (rv[tid + off] > rv[tid]) {
                    rv[tid] = rv[tid + off];
                    ri[tid] = ri[tid + off];
                }
            }
            __syncthreads();
        }
        if (tid == 0) {
            tv[it] = rv[0];
            tix[it] = ri[0];
            vals[ri[0]] = -3.0e38f;
        }
        __syncthreads();
    }
    if (tid == 0) {
        float mx = tv[0];
        float e[NK], s = 0.f;
        for (int i = 0; i < NK; ++i) { e[i] = expf(tv[i] - mx); s += e[i]; }
        for (int i = 0; i < NK; ++i) {
            wts[b * NK + i] = e[i] / s;
            dly[b * NK + i] = tix[i];
        }
    }
}

// ---------------------------------------------------------------------------
// Xagg[b,l,:] = sum_i w[b,i] * X[b,(l+d_i)%L,:], written split bf16 hi|lo
// ---------------------------------------------------------------------------
__global__ __launch_bounds__(256) void k_gather(const float* __restrict__ X,
                                                const float* __restrict__ wts,
                                                const int* __restrict__ dly,
                                                ushort_t* __restrict__ Xaggs) {
    __shared__ float sw[NK];
    __shared__ int sd[NK];
    int gid = blockIdx.x * 256 + threadIdx.x;
    int b = gid >> 19;
    int rem = gid & 524287;
    int l = rem >> 7;
    int c4 = rem & 127;
    if (threadIdx.x < NK) {
        sw[threadIdx.x] = wts[b * NK + threadIdx.x];
        sd[threadIdx.x] = dly[b * NK + threadIdx.x];
    }
    __syncthreads();
    const float4* Xb = (const float4*)X + (size_t)b * 524288;
    float4 s = make_float4(0.f, 0.f, 0.f, 0.f);
#pragma unroll
    for (int i = 0; i < NK; ++i) {
        int ls = (l + sd[i]) & (NL - 1);
        float4 v = Xb[(size_t)ls * 128 + c4];
        float w = sw[i];
        s.x += w * v.x;
        s.y += w * v.y;
        s.z += w * v.z;
        s.w += w * v.w;
    }
    ushort4 hi, lo;
    hi.x = f2bf(s.x); lo.x = f2bf(s.x - bf2f(hi.x));
    hi.y = f2bf(s.y); lo.y = f2bf(s.y - bf2f(hi.y));
    hi.z = f2bf(s.z); lo.z = f2bf(s.z - bf2f(hi.z));
    hi.w = f2bf(s.w); lo.w = f2bf(s.w - bf2f(hi.w));
    ushort_t* rowp = Xaggs + (size_t)(b * NL + l) * 1024;
    *(ushort4*)(rowp + c4 * 4) = hi;
    *(ushort4*)(rowp + 512 + c4 * 4) = lo;
}

// ---------------------------------------------------------------------------
extern "C" void kernel_launch(void* const* d_in, const int* in_sizes, int n_in,
                              void* d_out, int out_size, void* d_ws, size_t ws_size,
                              hipStream_t stream) {
    (void)in_sizes; (void)n_in; (void)out_size; (void)ws_size;
    const float* X  = (const float*)d_in[0];
    const float* Wq = (const float*)d_in[1];
    const float* Wk = (const float*)d_in[3];
    const float* Wv = (const float*)d_in[5];
    const float* bv = (const float*)d_in[6];
    const float* Wo = (const float*)d_in[7];
    const float* bo = (const float*)d_in[8];
    float* Out = (float*)d_out;

    char* ws = (char*)d_ws;
    const size_t MB = 1024 * 1024;
    // misc [0,5) MiB
    float*    M     = (float*)(ws + 0 * MB);             // 1 MB
    float*    Wov   = (float*)(ws + 1 * MB);             // 1 MB
    ushort_t* BsM   = (ushort_t*)(ws + 2 * MB);          // 1 MB
    ushort_t* BsW   = (ushort_t*)(ws + 3 * MB);          // 1 MB
    float*    bp    = (float*)(ws + 4 * MB);             // 2 KB
    float*    mc    = (float*)(ws + 4 * MB + 0x10000);   // 128 KB
    float*    wts   = (float*)(ws + 4 * MB + 0x40000);   // 256 B
    int*      dly   = (int*)(ws + 4 * MB + 0x41000);     // 256 B
    float2*   Cf    = (float2*)(ws + 4 * MB + 0x80000);  // 256 KB
    // partial [5,21) MiB (16 MiB exact)
    float2*   partial = (float2*)(ws + 5 * MB);
    // R0 [21,85): Xs (split X) -> XT (fp32 transpose) -> (unused)
    ushort_t* Xs    = (ushort_t*)(ws + 21 * MB);
    float*    XT    = (float*)(ws + 21 * MB);
    // R1 [85,149): YT -> Xaggs (YT dead after fft_fwd)
    float*    YT    = (float*)(ws + 85 * MB);
    ushort_t* Xaggs = (ushort_t*)(ws + 85 * MB);

    // 1) weight prep: M = Wq^T Wk ; Wov = Wo @ Wv ; bp ; bf16 splits
    k_smallgemm<<<dim3(32, 32), dim3(16, 16), 0, stream>>>(Wq, Wk, M, ND, 1, ND, 1);
    k_smallgemm<<<dim3(32, 32), dim3(16, 16), 0, stream>>>(Wo, Wv, Wov, 1, ND, ND, 1);
    k_biasprep<<<1, 512, 0, stream>>>(Wo, bv, bo, bp);
    k_split<<<256, 256, 0, stream>>>(M, BsM);
    k_split<<<256, 256, 0, stream>>>(Wov, BsW);

    // 2) Xs = split(X);  YT = (X @ M^T)^T  (MFMA, 256^2 tile, counted-vmcnt)
    k_split<<<16384, 256, 0, stream>>>(X, Xs);
    k_gemm_split<0><<<dim3(128, 2), 512, 0, stream>>>(Xs, BsM, nullptr, YT);

    // 3) XT = transpose(X)  (overwrites Xs region - Xs dead after GEMM1)
    k_transpose<<<dim3(128, 16, NB), dim3(32, 8), 0, stream>>>(X, XT);

    // 4) packed Stockham FFTs + channel-summed cross-spectrum; reduce; IFFT
    k_fft_fwd<<<512, 256, 0, stream>>>(XT, YT, partial);
    k_reduce<<<128, 256, 0, stream>>>(partial, Cf);
    k_ifft<<<NB, 256, 0, stream>>>(Cf, mc);

    // 5) top-8 delays + softmax weights
    k_topk<<<NB, 256, 0, stream>>>(mc, wts, dly);

    // 6) weighted circular gather, split-bf16 output (YT region, dead)
    k_gather<<<16384, 256, 0, stream>>>(X, wts, dly, Xaggs);

    // 7) Out = Xagg @ Wov^T + bp  (MFMA, 256^2 tile, counted-vmcnt)
    k_gemm_split<1><<<dim3(128, 2), 512, 0, stream>>>(Xaggs, BsW, bp, Out);
}

// Round 8
// 576.978 us; speedup vs baseline: 1.0368x; 1.0368x over previous
//
#include <hip/hip_runtime.h>
#include <math.h>

// Problem constants (B=8, L=4096, D=512, H=8, top_k = int(log(4096)) = 8)
#define NB 8
#define NL 4096
#define ND 512
#define NK 8

typedef unsigned short ushort_t;
typedef __bf16 bf16x8 __attribute__((ext_vector_type(8)));
typedef float f32x4 __attribute__((ext_vector_type(4)));

__device__ __forceinline__ unsigned short f2bf(float x) {
    unsigned u = __builtin_bit_cast(unsigned, x);
    u += 0x7fff + ((u >> 16) & 1);   // round-to-nearest-even
    return (unsigned short)(u >> 16);
}
__device__ __forceinline__ float bf2f(unsigned short b) {
    unsigned u = ((unsigned)b) << 16;
    return __builtin_bit_cast(float, u);
}

// ---------------------------------------------------------------------------
// Small GEMM: C[i,j] = sum_{k<512} A[k*sa_k + i*sa_i] * B[k*sb_k + j*sb_j]
// ---------------------------------------------------------------------------
__global__ void k_smallgemm(const float* __restrict__ A, const float* __restrict__ Bm,
                            float* __restrict__ C, int sa_k, int sa_i, int sb_k, int sb_j) {
    int i = blockIdx.y * 16 + threadIdx.y;
    int j = blockIdx.x * 16 + threadIdx.x;
    float acc = 0.f;
    for (int k = 0; k < ND; ++k)
        acc += A[k * sa_k + i * sa_i] * Bm[k * sb_k + j * sb_j];
    C[i * ND + j] = acc;
}

// bp[i] = bo[i] + sum_k Wo[i,k]*bv[k]
__global__ void k_biasprep(const float* __restrict__ Wo, const float* __restrict__ bv,
                           const float* __restrict__ bo, float* __restrict__ bp) {
    int i = blockIdx.x * blockDim.x + threadIdx.x;
    float acc = bo[i];
    for (int k = 0; k < ND; ++k) acc += Wo[i * ND + k] * bv[k];
    bp[i] = acc;
}

// Split fp32 rows into [row][0:512]=hi bf16, [row][512:1024]=lo bf16.
// grid = rows/2 blocks of 256 threads (each thread: 4 elements).
__global__ __launch_bounds__(256) void k_split(const float* __restrict__ src,
                                               ushort_t* __restrict__ dst) {
    int gid = blockIdx.x * 256 + threadIdx.x;
    int row = gid >> 7;
    int kc = (gid & 127) * 4;
    float4 v = *(const float4*)(src + (size_t)row * ND + kc);
    ushort4 hi, lo;
    hi.x = f2bf(v.x); lo.x = f2bf(v.x - bf2f(hi.x));
    hi.y = f2bf(v.y); lo.y = f2bf(v.y - bf2f(hi.y));
    hi.z = f2bf(v.z); lo.z = f2bf(v.z - bf2f(hi.z));
    hi.w = f2bf(v.w); lo.w = f2bf(v.w - bf2f(hi.w));
    *(ushort4*)(dst + (size_t)row * 1024 + kc) = hi;
    *(ushort4*)(dst + (size_t)row * 1024 + 512 + kc) = lo;
}

// ---------------------------------------------------------------------------
// Transpose X[b,l,c] -> XT[b,c,l]   (32x32 LDS tiles)
// ---------------------------------------------------------------------------
__global__ __launch_bounds__(256) void k_transpose(const float* __restrict__ X,
                                                   float* __restrict__ XT) {
    __shared__ float t[32][33];
    int b  = blockIdx.z;
    int l0 = blockIdx.x * 32;
    int c0 = blockIdx.y * 32;
    const float* Xb = X + (size_t)b * NL * ND;
    float* XTb = XT + (size_t)b * ND * NL;
    int tx = threadIdx.x, ty = threadIdx.y;  // 32 x 8
#pragma unroll
    for (int j = 0; j < 4; ++j)
        t[ty + j * 8][tx] = Xb[(size_t)(l0 + ty + j * 8) * ND + c0 + tx];
    __syncthreads();
#pragma unroll
    for (int j = 0; j < 4; ++j)
        XTb[(size_t)(c0 + ty + j * 8) * NL + l0 + tx] = t[tx][ty + j * 8];
}

// ---------------------------------------------------------------------------
// Split-bf16 MFMA GEMM:  C[r,n] = sum_k A[r,k] * Brow[n,k]
// A, B both pre-split bf16 [rows][1024] = hi(512) | lo(512).
// R7: R6's counted-vmcnt schedule + R1's COALESCED-SOURCE staging layout.
// R3/R4/R6's fragment-order permutation made each DMA wave-inst read 64
// scattered 16B chunks (16 rows x 2KB stride) -> 4x L2-side amplification
// (~4.7K cyc/iter). R1 layout: chunk q -> row r=q>>2, chunk c=(q&3)^((r>>1)&3)
// so 4 consecutive lanes cover one row's full 64B (no amplification); the
// read-side XOR pattern is <=2-way bank conflict (free). The 1.9-2.7e7
// conflict counter is the DMA write-path tax, layout-invariant.
// Schedule (T4): 2-deep prefetch; per iter: s_waitcnt vmcnt(8) + s_barrier ->
// COMPUTE -> lgkmcnt(0) + s_barrier -> STAGE(t+2). Never vmcnt(0) in loop.
// setprio(1) around MFMA cluster (T5); sched_barrier(0) fences (rule #18).
// 256x256 tile, 8 waves (2M x 4N), BK=32, 128KB LDS, 1 block/CU, grid=256.
// 3-term split: Ah*Bh + Ah*Bl + Al*Bh.
// XCD-chunked tile remap keeps A/B panels L2-resident per XCD.
// EPI=0: write transposed YT[b,n,l]; EPI=1: bias + plain [r,n].
// ---------------------------------------------------------------------------
template <int EPI>
__global__ __launch_bounds__(512, 2) void k_gemm_split(const ushort_t* __restrict__ As,
                                                       const ushort_t* __restrict__ Bs,
                                                       const float* __restrict__ bp,
                                                       float* __restrict__ Out) {
    struct Buf { ushort_t ahi[256 * 32]; ushort_t alo[256 * 32];
                 ushort_t bhi[256 * 32]; ushort_t blo[256 * 32]; };   // 64 KB
    __shared__ union USm {
        Buf s[2];                                                      // 128 KB
        float t[32 * 257];                                             // epilogue transpose
    } sm;
    const int tid = threadIdx.x;
    // hw linear block id -> XCD-chunked bijection (256 = 8 XCDs * 32)
    const int flat = blockIdx.x + (blockIdx.y << 7);   // gridDim.x = 128
    const int wswz = ((flat & 7) << 5) + (flat >> 3);
    const int l0 = (wswz >> 1) * 256;   // 128 l-tiles
    const int n0 = (wswz & 1) * 256;    // 2 n-tiles, adjacent per A-panel
    const int lane = tid & 63;
    const int w = tid >> 6;             // 0..7
    const int wr = (w & 1) * 128;       // wave row-group: 0 / 128
    const int wc = (w >> 1) * 64;       // wave col-group: 0/64/128/192
    const int m = lane & 15;
    const int quad = lane >> 4;

    f32x4 acc[8][4];
#pragma unroll
    for (int i = 0; i < 8; ++i)
#pragma unroll
        for (int j = 0; j < 4; ++j) acc[i][j] = (f32x4){0.f, 0.f, 0.f, 0.f};

    // Coalesced-source staging: chunk q (0..1023): row r=q>>2, source chunk
    // c=(q&3)^((r>>1)&3). 4 consecutive lanes read one row's contiguous 64B
    // (chunk-permuted within). LDS dest linear q*16B (wave-uniform + lane*16).
    // Exactly 8 global_load_lds per thread => vmcnt granularity 8 per STAGE.
    auto STAGE = [&](int bf, int k0) {
#pragma unroll
        for (int v = 0; v < 2; ++v) {
            int q = v * 512 + tid;
            int r = q >> 2;
            int c = (q & 3) ^ ((r >> 1) & 3);
            const ushort_t* asrc = As + (size_t)(l0 + r) * 1024 + k0 + c * 8;
            __builtin_amdgcn_global_load_lds(
                (const __attribute__((address_space(1))) unsigned int*)asrc,
                (__attribute__((address_space(3))) unsigned int*)&sm.s[bf].ahi[q * 8], 16, 0, 0);
            __builtin_amdgcn_global_load_lds(
                (const __attribute__((address_space(1))) unsigned int*)(asrc + 512),
                (__attribute__((address_space(3))) unsigned int*)&sm.s[bf].alo[q * 8], 16, 0, 0);
            const ushort_t* bsrc = Bs + (size_t)(n0 + r) * 1024 + k0 + c * 8;
            __builtin_amdgcn_global_load_lds(
                (const __attribute__((address_space(1))) unsigned int*)bsrc,
                (__attribute__((address_space(3))) unsigned int*)&sm.s[bf].bhi[q * 8], 16, 0, 0);
            __builtin_amdgcn_global_load_lds(
                (const __attribute__((address_space(1))) unsigned int*)(bsrc + 512),
                (__attribute__((address_space(3))) unsigned int*)&sm.s[bf].blo[q * 8], 16, 0, 0);
        }
    };

    // Fragment read: row's chunk for this quad sits at position quad^((row>>1)&3)
    // within the row's 4 chunks: off = row*32 + (quad^((row>>1)&3))*8.
    // <=2-way bank aliasing across the wave (free).
    auto COMPUTE = [&](int bf) {
        bf16x8 ah[8], al[8];
#pragma unroll
        for (int i = 0; i < 8; ++i) {
            int row = wr + 16 * i + m;
            int off = row * 32 + ((quad ^ ((row >> 1) & 3)) * 8);
            ah[i] = *(const bf16x8*)&sm.s[bf].ahi[off];
            al[i] = *(const bf16x8*)&sm.s[bf].alo[off];
        }
        __builtin_amdgcn_s_setprio(1);
#pragma unroll
        for (int j = 0; j < 4; ++j) {
            int row = wc + 16 * j + m;
            int off = row * 32 + ((quad ^ ((row >> 1) & 3)) * 8);
            bf16x8 bh = *(const bf16x8*)&sm.s[bf].bhi[off];
            bf16x8 bl = *(const bf16x8*)&sm.s[bf].blo[off];
#pragma unroll
            for (int i = 0; i < 8; ++i) {
                acc[i][j] = __builtin_amdgcn_mfma_f32_16x16x32_bf16(ah[i], bh, acc[i][j], 0, 0, 0);
                acc[i][j] = __builtin_amdgcn_mfma_f32_16x16x32_bf16(ah[i], bl, acc[i][j], 0, 0, 0);
                acc[i][j] = __builtin_amdgcn_mfma_f32_16x16x32_bf16(al[i], bh, acc[i][j], 0, 0, 0);
            }
        }
        __builtin_amdgcn_s_setprio(0);
    };

    // prologue: 2-deep prefetch (16 loads/thread in flight)
    STAGE(0, 0);
    STAGE(1, 32);
    for (int t = 0; t < 15; ++t) {
        // wait for tile t's loads; tile t+1's 8 loads stay in flight
        asm volatile("s_waitcnt vmcnt(8)" ::: "memory");
        __builtin_amdgcn_sched_barrier(0);
        __builtin_amdgcn_s_barrier();      // all waves' tile-t data in LDS
        COMPUTE(t & 1);
        asm volatile("s_waitcnt lgkmcnt(0)" ::: "memory");
        __builtin_amdgcn_sched_barrier(0);
        __builtin_amdgcn_s_barrier();      // all waves done reading buf[t&1]
        __builtin_amdgcn_sched_barrier(0);
        if (t < 14) STAGE(t & 1, (t + 2) * 32);
    }
    asm volatile("s_waitcnt vmcnt(0)" ::: "memory");
    __builtin_amdgcn_sched_barrier(0);
    __builtin_amdgcn_s_barrier();
    COMPUTE(1);   // tile 15

    if (EPI == 1) {
        // bias + plain [row, col]
#pragma unroll
        for (int j = 0; j < 4; ++j) {
            int col = n0 + wc + 16 * j + m;
            float bv = bp[col];
#pragma unroll
            for (int i = 0; i < 8; ++i) {
                size_t rbase = (size_t)(l0 + wr + 16 * i + quad * 4) * ND + col;
#pragma unroll
                for (int r = 0; r < 4; ++r)
                    Out[rbase + (size_t)r * ND] = acc[i][j][r] + bv;
            }
        }
    } else {
        // transposed write YT[b, n, l] via LDS, 32-col chunks (8 chunks)
#pragma unroll
        for (int c = 0; c < 8; ++c) {
            __syncthreads();
            if ((wc >> 6) == (c >> 1)) {
                int jb = (c & 1) * 2;
#pragma unroll
                for (int jj = 0; jj < 2; ++jj) {
                    int j = jb + jj;
                    int cl = 16 * jj + m;
#pragma unroll
                    for (int i = 0; i < 8; ++i)
#pragma unroll
                        for (int r = 0; r < 4; ++r)
                            sm.t[cl * 257 + wr + 16 * i + quad * 4 + r] = acc[i][j][r];
                }
            }
            __syncthreads();
#pragma unroll
            for (int it = 0; it < 16; ++it) {
                int idx = it * 512 + tid;
                int cl = idx >> 8;
                int row = idx & 255;
                int rg = l0 + row;
                Out[((size_t)((rg >> 12) * ND + n0 + c * 32 + cl)) * NL + (rg & 4095)] =
                    sm.t[cl * 257 + row];
            }
        }
    }
}

// ---------------------------------------------------------------------------
// 16-point in-register DFT (natural in/out). DIR=+1 fwd (e^{-i}), -1 inverse.
// ---------------------------------------------------------------------------
template <int DIR>
__device__ __forceinline__ void fft16(float2* v) {
    const float ct[8] = {1.f, 0.923879533f, 0.707106781f, 0.382683432f,
                         0.f, -0.382683432f, -0.707106781f, -0.923879533f};
    const float st[8] = {0.f, 0.382683432f, 0.707106781f, 0.923879533f,
                         1.f, 0.923879533f, 0.707106781f, 0.382683432f};
    const int br[16] = {0, 8, 4, 12, 2, 10, 6, 14, 1, 9, 5, 13, 3, 11, 7, 15};
    float2 a[16];
#pragma unroll
    for (int i = 0; i < 16; ++i) a[i] = v[br[i]];
#pragma unroll
    for (int s = 1; s <= 4; ++s) {
        const int L = 1 << s, h = L >> 1;
#pragma unroll
        for (int g = 0; g < 16; g += L)
#pragma unroll
            for (int p = 0; p < h; ++p) {
                int k = p << (4 - s);
                float wr = ct[k];
                float wi = (DIR > 0) ? -st[k] : st[k];
                int i1 = g + p, i2 = i1 + h;
                float tr = wr * a[i2].x - wi * a[i2].y;
                float ti = wr * a[i2].y + wi * a[i2].x;
                a[i2].x = a[i1].x - tr; a[i2].y = a[i1].y - ti;
                a[i1].x += tr;          a[i1].y += ti;
            }
    }
#pragma unroll
    for (int i = 0; i < 16; ++i) v[i] = a[i];
}

__device__ __forceinline__ float2 cmul(float2 a, float2 b) {
    return make_float2(a.x * b.x - a.y * b.y, a.x * b.y + a.y * b.x);
}
#define PADI(i) ((i) + ((i) >> 4))

// ---------------------------------------------------------------------------
// Forward: per (batch, group of 8 channels): z = x + i*y, 4096-pt Stockham
// radix-16 FFT (3 stages), accumulate cross-spectrum
// X_c(f)*conj(Y_c(f)) = Im(Z_f*Z_{-f})/2 + i*(|Z_f|^2-|Z_{-f}|^2)/4
// into partial[b, g, f].
// ---------------------------------------------------------------------------
__global__ __launch_bounds__(256) void k_fft_fwd(const float* __restrict__ XT,
                                                 const float* __restrict__ YT,
                                                 float2* __restrict__ partial) {
    __shared__ float2 data[4352];   // 4096 + pad
    const int t = threadIdx.x;
    const int b = blockIdx.x >> 6;
    const int g = blockIdx.x & 63;

    float sv, cv;
    sincosf(-6.283185307179586f * (float)(t & 15) / 256.0f, &sv, &cv);
    const float2 w2 = make_float2(cv, sv);
    sincosf(-6.283185307179586f * (float)t / 4096.0f, &sv, &cv);
    const float2 w3 = make_float2(cv, sv);

    float2 acc[16];
#pragma unroll
    for (int r = 0; r < 16; ++r) acc[r] = make_float2(0.f, 0.f);

    for (int ch = 0; ch < 8; ++ch) {
        int c = g * 8 + ch;
        const float* xr = XT + ((size_t)b * ND + c) * NL;
        const float* yr = YT + ((size_t)b * ND + c) * NL;
        float2 v[16];
        // stage 1 (Ns=1): read natural, fft16, write idx 16t+m
#pragma unroll
        for (int mm = 0; mm < 16; ++mm)
            v[mm] = make_float2(xr[t + 256 * mm], yr[t + 256 * mm]);
        fft16<1>(v);
        __syncthreads();   // prior channel's pair-reads done
#pragma unroll
        for (int mm = 0; mm < 16; ++mm) data[PADI(16 * t + mm)] = v[mm];
        __syncthreads();
        // stage 2 (Ns=16)
#pragma unroll
        for (int mm = 0; mm < 16; ++mm) v[mm] = data[PADI(t + 256 * mm)];
        {
            float2 wm = make_float2(1.f, 0.f);
#pragma unroll
            for (int mm = 1; mm < 16; ++mm) { wm = cmul(wm, w2); v[mm] = cmul(v[mm], wm); }
        }
        fft16<1>(v);
        __syncthreads();
        {
            int base = (t >> 4) * 256 + (t & 15);
#pragma unroll
            for (int mm = 0; mm < 16; ++mm) data[PADI(base + 16 * mm)] = v[mm];
        }
        __syncthreads();
        // stage 3 (Ns=256) -> natural-order Z in registers
#pragma unroll
        for (int mm = 0; mm < 16; ++mm) v[mm] = data[PADI(t + 256 * mm)];
        {
            float2 wm = make_float2(1.f, 0.f);
#pragma unroll
            for (int mm = 1; mm < 16; ++mm) { wm = cmul(wm, w3); v[mm] = cmul(v[mm], wm); }
        }
        fft16<1>(v);
        __syncthreads();
#pragma unroll
        for (int mm = 0; mm < 16; ++mm) data[PADI(t + 256 * mm)] = v[mm];
        __syncthreads();
        // cross-spectrum accumulate
#pragma unroll
        for (int mm = 0; mm < 16; ++mm) {
            int f = t + 256 * mm;
            float2 A = v[mm];
            float2 Bz = data[PADI((4096 - f) & 4095)];
            acc[mm].x += 0.5f * (A.x * Bz.y + A.y * Bz.x);
            acc[mm].y += 0.25f * ((A.x * A.x + A.y * A.y) - (Bz.x * Bz.x + Bz.y * Bz.y));
        }
    }
    float2* out = partial + ((size_t)b * 64 + g) * 4096;
#pragma unroll
    for (int mm = 0; mm < 16; ++mm) out[256 * mm + t] = acc[mm];
}

// Reduce 64 partials -> Cf[b][f]
__global__ __launch_bounds__(256) void k_reduce(const float2* __restrict__ partial,
                                                float2* __restrict__ Cf) {
    int b = blockIdx.x >> 4;
    int f = (blockIdx.x & 15) * 256 + threadIdx.x;
    float2 s = make_float2(0.f, 0.f);
    for (int g = 0; g < 64; ++g) {
        float2 v = partial[((size_t)(b * 64 + g)) * 4096 + f];
        s.x += v.x; s.y += v.y;
    }
    Cf[(size_t)b * 4096 + f] = s;
}

// ---------------------------------------------------------------------------
// Fused: inverse 4096-pt Stockham on Cf -> mean_corr (in LDS) -> top-8 +
// softmax per batch. Saves a kernel launch + the mc global round-trip.
// ---------------------------------------------------------------------------
__global__ __launch_bounds__(256) void k_ifft_topk(const float2* __restrict__ Cf,
                                                   float* __restrict__ wts,
                                                   int* __restrict__ dly) {
    __shared__ float2 data[4352];
    __shared__ float vals[4096];
    __shared__ float rv[256];
    __shared__ int ri[256];
    __shared__ float tv[NK];
    __shared__ int tix[NK];
    const int t = threadIdx.x;
    const int b = blockIdx.x;
    float sv, cv;
    sincosf(6.283185307179586f * (float)(t & 15) / 256.0f, &sv, &cv);
    const float2 w2 = make_float2(cv, sv);
    sincosf(6.283185307179586f * (float)t / 4096.0f, &sv, &cv);
    const float2 w3 = make_float2(cv, sv);

    float2 v[16];
#pragma unroll
    for (int mm = 0; mm < 16; ++mm) v[mm] = Cf[(size_t)b * 4096 + t + 256 * mm];
    fft16<-1>(v);
#pragma unroll
    for (int mm = 0; mm < 16; ++mm) data[PADI(16 * t + mm)] = v[mm];
    __syncthreads();
#pragma unroll
    for (int mm = 0; mm < 16; ++mm) v[mm] = data[PADI(t + 256 * mm)];
    {
        float2 wm = make_float2(1.f, 0.f);
#pragma unroll
        for (int mm = 1; mm < 16; ++mm) { wm = cmul(wm, w2); v[mm] = cmul(v[mm], wm); }
    }
    fft16<-1>(v);
    __syncthreads();
    {
        int base = (t >> 4) * 256 + (t & 15);
#pragma unroll
        for (int mm = 0; mm < 16; ++mm) data[PADI(base + 16 * mm)] = v[mm];
    }
    __syncthreads();
#pragma unroll
    for (int mm = 0; mm < 16; ++mm) v[mm] = data[PADI(t + 256 * mm)];
    {
        float2 wm = make_float2(1.f, 0.f);
#pragma unroll
        for (int mm = 1; mm < 16; ++mm) { wm = cmul(wm, w3); v[mm] = cmul(v[mm], wm); }
    }
    fft16<-1>(v);
    const float scale = 1.0f / (4096.0f * 512.0f);
#pragma unroll
    for (int mm = 0; mm < 16; ++mm)
        vals[t + 256 * mm] = v[mm].x * scale;
    __syncthreads();

    // top-8 + softmax
    for (int it = 0; it < NK; ++it) {
        float bv = -3.0e38f;
        int bi = 0;
        for (int tt = t; tt < 4096; tt += 256) {
            float vv = vals[tt];
            if (vv > bv) { bv = vv; bi = tt; }
        }
        rv[t] = bv;
        ri[t] = bi;
        __syncthreads();
        for (int off = 128; off > 0; off >>= 1) {
            if (t < off) {
                if (rv[t + off] > rv[t]) {
                    rv[t] = rv[t + off];
                    ri[t] = ri[t + off];
                }
            }
            __syncthreads();
        }
        if (t == 0) {
            tv[it] = rv[0];
            tix[it] = ri[0];
            vals[ri[0]] = -3.0e38f;
        }
        __syncthreads();
    }
    if (t == 0) {
        float mx = tv[0];
        float e[NK], s = 0.f;
        for (int i = 0; i < NK; ++i) { e[i] = expf(tv[i] - mx); s += e[i]; }
        for (int i = 0; i < NK; ++i) {
            wts[b * NK + i] = e[i] / s;
            dly[b * NK + i] = tix[i];
        }
    }
}

// ---------------------------------------------------------------------------
// Xagg[b,l,:] = sum_i w[b,i] * X[b,(l+d_i)%L,:], written split bf16 hi|lo
// ---------------------------------------------------------------------------
__global__ __launch_bounds__(256) void k_gather(const float* __restrict__ X,
                                                const float* __restrict__ wts,
                                                const int* __restrict__ dly,
                                                ushort_t* __restrict__ Xaggs) {
    __shared__ float sw[NK];
    __shared__ int sd[NK];
    int gid = blockIdx.x * 256 + threadIdx.x;
    int b = gid >> 19;
    int rem = gid & 524287;
    int l = rem >> 7;
    int c4 = rem & 127;
    if (threadIdx.x < NK) {
        sw[threadIdx.x] = wts[b * NK + threadIdx.x];
        sd[threadIdx.x] = dly[b * NK + threadIdx.x];
    }
    __syncthreads();
    const float4* Xb = (const float4*)X + (size_t)b * 524288;
    float4 s = make_float4(0.f, 0.f, 0.f, 0.f);
#pragma unroll
    for (int i = 0; i < NK; ++i) {
        int ls = (l + sd[i]) & (NL - 1);
        float4 v = Xb[(size_t)ls * 128 + c4];
        float w = sw[i];
        s.x += w * v.x;
        s.y += w * v.y;
        s.z += w * v.z;
        s.w += w * v.w;
    }
    ushort4 hi, lo;
    hi.x = f2bf(s.x); lo.x = f2bf(s.x - bf2f(hi.x));
    hi.y = f2bf(s.y); lo.y = f2bf(s.y - bf2f(hi.y));
    hi.z = f2bf(s.z); lo.z = f2bf(s.z - bf2f(hi.z));
    hi.w = f2bf(s.w); lo.w = f2bf(s.w - bf2f(hi.w));
    ushort_t* rowp = Xaggs + (size_t)(b * NL + l) * 1024;
    *(ushort4*)(rowp + c4 * 4) = hi;
    *(ushort4*)(rowp + 512 + c4 * 4) = lo;
}

// ---------------------------------------------------------------------------
extern "C" void kernel_launch(void* const* d_in, const int* in_sizes, int n_in,
                              void* d_out, int out_size, void* d_ws, size_t ws_size,
                              hipStream_t stream) {
    (void)in_sizes; (void)n_in; (void)out_size; (void)ws_size;
    const float* X  = (const float*)d_in[0];
    const float* Wq = (const float*)d_in[1];
    const float* Wk = (const float*)d_in[3];
    const float* Wv = (const float*)d_in[5];
    const float* bv = (const float*)d_in[6];
    const float* Wo = (const float*)d_in[7];
    const float* bo = (const float*)d_in[8];
    float* Out = (float*)d_out;

    char* ws = (char*)d_ws;
    const size_t MB = 1024 * 1024;
    // misc [0,5) MiB
    float*    M     = (float*)(ws + 0 * MB);             // 1 MB
    float*    Wov   = (float*)(ws + 1 * MB);             // 1 MB
    ushort_t* BsM   = (ushort_t*)(ws + 2 * MB);          // 1 MB
    ushort_t* BsW   = (ushort_t*)(ws + 3 * MB);          // 1 MB
    float*    bp    = (float*)(ws + 4 * MB);             // 2 KB
    float*    wts   = (float*)(ws + 4 * MB + 0x40000);   // 256 B
    int*      dly   = (int*)(ws + 4 * MB + 0x41000);     // 256 B
    float2*   Cf    = (float2*)(ws + 4 * MB + 0x80000);  // 256 KB
    // partial [5,21) MiB (16 MiB exact)
    float2*   partial = (float2*)(ws + 5 * MB);
    // R0 [21,85): Xs (split X) -> XT (fp32 transpose) -> (unused)
    ushort_t* Xs    = (ushort_t*)(ws + 21 * MB);
    float*    XT    = (float*)(ws + 21 * MB);
    // R1 [85,149): YT -> Xaggs (YT dead after fft_fwd)
    float*    YT    = (float*)(ws + 85 * MB);
    ushort_t* Xaggs = (ushort_t*)(ws + 85 * MB);

    // 1) weight prep: M = Wq^T Wk ; Wov = Wo @ Wv ; bp ; bf16 splits
    k_smallgemm<<<dim3(32, 32), dim3(16, 16), 0, stream>>>(Wq, Wk, M, ND, 1, ND, 1);
    k_smallgemm<<<dim3(32, 32), dim3(16, 16), 0, stream>>>(Wo, Wv, Wov, 1, ND, ND, 1);
    k_biasprep<<<1, 512, 0, stream>>>(Wo, bv, bo, bp);
    k_split<<<256, 256, 0, stream>>>(M, BsM);
    k_split<<<256, 256, 0, stream>>>(Wov, BsW);

    // 2) Xs = split(X);  YT = (X @ M^T)^T  (MFMA, 256^2, coalesced-source DMA)
    k_split<<<16384, 256, 0, stream>>>(X, Xs);
    k_gemm_split<0><<<dim3(128, 2), 512, 0, stream>>>(Xs, BsM, nullptr, YT);

    // 3) XT = transpose(X)  (overwrites Xs region - Xs dead after GEMM1)
    k_transpose<<<dim3(128, 16, NB), dim3(32, 8), 0, stream>>>(X, XT);

    // 4) packed Stockham FFTs + channel-summed cross-spectrum; reduce;
    //    fused IFFT + top-8 + softmax
    k_fft_fwd<<<512, 256, 0, stream>>>(XT, YT, partial);
    k_reduce<<<128, 256, 0, stream>>>(partial, Cf);
    k_ifft_topk<<<NB, 256, 0, stream>>>(Cf, wts, dly);

    // 6) weighted circular gather, split-bf16 output (YT region, dead)
    k_gather<<<16384, 256, 0, stream>>>(X, wts, dly, Xaggs);

    // 7) Out = Xagg @ Wov^T + bp  (MFMA, 256^2, coalesced-source DMA)
    k_gemm_split<1><<<dim3(128, 2), 512, 0, stream>>>(Xaggs, BsW, bp, Out);
}

// Round 9
// 574.236 us; speedup vs baseline: 1.0417x; 1.0048x over previous
//
#include <hip/hip_runtime.h>
#include <math.h>

// Problem constants (B=8, L=4096, D=512, H=8, top_k = int(log(4096)) = 8)
#define NB 8
#define NL 4096
#define ND 512
#define NK 8

typedef unsigned short ushort_t;
typedef __bf16 bf16x8 __attribute__((ext_vector_type(8)));
typedef float f32x4 __attribute__((ext_vector_type(4)));

__device__ __forceinline__ unsigned short f2bf(float x) {
    unsigned u = __builtin_bit_cast(unsigned, x);
    u += 0x7fff + ((u >> 16) & 1);   // round-to-nearest-even
    return (unsigned short)(u >> 16);
}
__device__ __forceinline__ float bf2f(unsigned short b) {
    unsigned u = ((unsigned)b) << 16;
    return __builtin_bit_cast(float, u);
}

// ---------------------------------------------------------------------------
// Small GEMM: C[i,j] = sum_{k<512} A[k*sa_k + i*sa_i] * B[k*sb_k + j*sb_j]
// ---------------------------------------------------------------------------
__global__ void k_smallgemm(const float* __restrict__ A, const float* __restrict__ Bm,
                            float* __restrict__ C, int sa_k, int sa_i, int sb_k, int sb_j) {
    int i = blockIdx.y * 16 + threadIdx.y;
    int j = blockIdx.x * 16 + threadIdx.x;
    float acc = 0.f;
    for (int k = 0; k < ND; ++k)
        acc += A[k * sa_k + i * sa_i] * Bm[k * sb_k + j * sb_j];
    C[i * ND + j] = acc;
}

// bp[i] = bo[i] + sum_k Wo[i,k]*bv[k]
__global__ void k_biasprep(const float* __restrict__ Wo, const float* __restrict__ bv,
                           const float* __restrict__ bo, float* __restrict__ bp) {
    int i = blockIdx.x * blockDim.x + threadIdx.x;
    float acc = bo[i];
    for (int k = 0; k < ND; ++k) acc += Wo[i * ND + k] * bv[k];
    bp[i] = acc;
}

// Split fp32 rows into [row][0:512]=hi bf16, [row][512:1024]=lo bf16.
// grid = rows/2 blocks of 256 threads (each thread: 4 elements).
__global__ __launch_bounds__(256) void k_split(const float* __restrict__ src,
                                               ushort_t* __restrict__ dst) {
    int gid = blockIdx.x * 256 + threadIdx.x;
    int row = gid >> 7;
    int kc = (gid & 127) * 4;
    float4 v = *(const float4*)(src + (size_t)row * ND + kc);
    ushort4 hi, lo;
    hi.x = f2bf(v.x); lo.x = f2bf(v.x - bf2f(hi.x));
    hi.y = f2bf(v.y); lo.y = f2bf(v.y - bf2f(hi.y));
    hi.z = f2bf(v.z); lo.z = f2bf(v.z - bf2f(hi.z));
    hi.w = f2bf(v.w); lo.w = f2bf(v.w - bf2f(hi.w));
    *(ushort4*)(dst + (size_t)row * 1024 + kc) = hi;
    *(ushort4*)(dst + (size_t)row * 1024 + 512 + kc) = lo;
}

// ---------------------------------------------------------------------------
// Transpose X[b,l,c] -> XT[b,c,l]   (32x32 LDS tiles)
// ---------------------------------------------------------------------------
__global__ __launch_bounds__(256) void k_transpose(const float* __restrict__ X,
                                                   float* __restrict__ XT) {
    __shared__ float t[32][33];
    int b  = blockIdx.z;
    int l0 = blockIdx.x * 32;
    int c0 = blockIdx.y * 32;
    const float* Xb = X + (size_t)b * NL * ND;
    float* XTb = XT + (size_t)b * ND * NL;
    int tx = threadIdx.x, ty = threadIdx.y;  // 32 x 8
#pragma unroll
    for (int j = 0; j < 4; ++j)
        t[ty + j * 8][tx] = Xb[(size_t)(l0 + ty + j * 8) * ND + c0 + tx];
    __syncthreads();
#pragma unroll
    for (int j = 0; j < 4; ++j)
        XTb[(size_t)(c0 + ty + j * 8) * NL + l0 + tx] = t[tx][ty + j * 8];
}

// ---------------------------------------------------------------------------
// Split-bf16 MFMA GEMM:  C[r,n] = sum_k A[r,k] * Brow[n,k]
// A, B both pre-split bf16 [rows][1024] = hi(512) | lo(512).
// R8: fine-phase schedule (m201 port). R1-R7 all plateau at ~530-600 TF =
// the measured 2-barrier-per-K-step structure ceiling (m233: 607 TF; no
// single component removal helps). Per K-iter, 4 phases (one per B col-group
// j): {ds_read bh/bl (phase0 also A-frags) | issue 4 stage loads (phases
// 0-1) -> s_barrier -> lgkmcnt(0)+sched_barrier -> setprio(1) -> 24 MFMA ->
// setprio(0) -> s_barrier}. 1-deep prefetch, WAR-safe: tile t+1 stages into
// buf c^1 (fully read in iter t-1, sealed by its exit barrier). Tile-ready:
// per-wave vmcnt(0) folded into phase-3 exit barrier (loads get phases 2-3
// ~2.5K cyc of cover, drain returns ~immediately).
// Staging layout (R7): coalesced source, chunk q -> row r=q>>2, chunk
// c=(q&3)^((r>>1)&3); fragment read off = row*32 + (quad^((row>>1)&3))*8
// (<=2-way bank alias, free). 256x256 tile, 8 waves (2Mx4N), BK=32, 128KB
// LDS, 1 block/CU, grid=256. 3-term split: Ah*Bh + Ah*Bl + Al*Bh.
// XCD-chunked tile remap keeps A/B panels L2-resident per XCD.
// EPI=0: write transposed YT[b,n,l]; EPI=1: bias + plain [r,n].
// ---------------------------------------------------------------------------
template <int EPI>
__global__ __launch_bounds__(512, 2) void k_gemm_split(const ushort_t* __restrict__ As,
                                                       const ushort_t* __restrict__ Bs,
                                                       const float* __restrict__ bp,
                                                       float* __restrict__ Out) {
    struct Buf { ushort_t ahi[256 * 32]; ushort_t alo[256 * 32];
                 ushort_t bhi[256 * 32]; ushort_t blo[256 * 32]; };   // 64 KB
    __shared__ union USm {
        Buf s[2];                                                      // 128 KB
        float t[32 * 257];                                             // epilogue transpose
    } sm;
    const int tid = threadIdx.x;
    // hw linear block id -> XCD-chunked bijection (256 = 8 XCDs * 32)
    const int flat = blockIdx.x + (blockIdx.y << 7);   // gridDim.x = 128
    const int wswz = ((flat & 7) << 5) + (flat >> 3);
    const int l0 = (wswz >> 1) * 256;   // 128 l-tiles
    const int n0 = (wswz & 1) * 256;    // 2 n-tiles, adjacent per A-panel
    const int lane = tid & 63;
    const int w = tid >> 6;             // 0..7
    const int wr = (w & 1) * 128;       // wave row-group: 0 / 128
    const int wc = (w >> 1) * 64;       // wave col-group: 0/64/128/192
    const int m = lane & 15;
    const int quad = lane >> 4;

    f32x4 acc[8][4];
#pragma unroll
    for (int i = 0; i < 8; ++i)
#pragma unroll
        for (int j = 0; j < 4; ++j) acc[i][j] = (f32x4){0.f, 0.f, 0.f, 0.f};

    // Stage one half-tile (4 gload_lds per thread). Coalesced source:
    // chunk q: row r=q>>2, source chunk c=(q&3)^((r>>1)&3); LDS dest linear.
    auto STAGE_HALF = [&](int bf, int k0, int v) {
        int q = v * 512 + tid;
        int r = q >> 2;
        int c = (q & 3) ^ ((r >> 1) & 3);
        const ushort_t* asrc = As + (size_t)(l0 + r) * 1024 + k0 + c * 8;
        __builtin_amdgcn_global_load_lds(
            (const __attribute__((address_space(1))) unsigned int*)asrc,
            (__attribute__((address_space(3))) unsigned int*)&sm.s[bf].ahi[q * 8], 16, 0, 0);
        __builtin_amdgcn_global_load_lds(
            (const __attribute__((address_space(1))) unsigned int*)(asrc + 512),
            (__attribute__((address_space(3))) unsigned int*)&sm.s[bf].alo[q * 8], 16, 0, 0);
        const ushort_t* bsrc = Bs + (size_t)(n0 + r) * 1024 + k0 + c * 8;
        __builtin_amdgcn_global_load_lds(
            (const __attribute__((address_space(1))) unsigned int*)bsrc,
            (__attribute__((address_space(3))) unsigned int*)&sm.s[bf].bhi[q * 8], 16, 0, 0);
        __builtin_amdgcn_global_load_lds(
            (const __attribute__((address_space(1))) unsigned int*)(bsrc + 512),
            (__attribute__((address_space(3))) unsigned int*)&sm.s[bf].blo[q * 8], 16, 0, 0);
    };

    // prologue: stage tile 0 (both halves); drain; barrier
    STAGE_HALF(0, 0, 0);
    STAGE_HALF(0, 0, 1);
    asm volatile("s_waitcnt vmcnt(0)" ::: "memory");
    __builtin_amdgcn_sched_barrier(0);
    __builtin_amdgcn_s_barrier();

    for (int t = 0; t < 16; ++t) {
        const int c = t & 1;
        bf16x8 ah[8], al[8];
#pragma unroll
        for (int i = 0; i < 8; ++i) {
            int row = wr + 16 * i + m;
            int off = row * 32 + ((quad ^ ((row >> 1) & 3)) * 8);
            ah[i] = *(const bf16x8*)&sm.s[c].ahi[off];
            al[i] = *(const bf16x8*)&sm.s[c].alo[off];
        }
#pragma unroll
        for (int j = 0; j < 4; ++j) {
            int row = wc + 16 * j + m;
            int off = row * 32 + ((quad ^ ((row >> 1) & 3)) * 8);
            bf16x8 bh = *(const bf16x8*)&sm.s[c].bhi[off];
            bf16x8 bl = *(const bf16x8*)&sm.s[c].blo[off];
            // fine interleave: issue next-tile stage loads during phases 0,1
            if (t < 15 && j < 2) STAGE_HALF(c ^ 1, (t + 1) * 32, j);
            __builtin_amdgcn_s_barrier();               // phase entry align
            asm volatile("s_waitcnt lgkmcnt(0)" ::: "memory");
            __builtin_amdgcn_sched_barrier(0);
            __builtin_amdgcn_s_setprio(1);
#pragma unroll
            for (int i = 0; i < 8; ++i) {
                acc[i][j] = __builtin_amdgcn_mfma_f32_16x16x32_bf16(ah[i], bh, acc[i][j], 0, 0, 0);
                acc[i][j] = __builtin_amdgcn_mfma_f32_16x16x32_bf16(ah[i], bl, acc[i][j], 0, 0, 0);
                acc[i][j] = __builtin_amdgcn_mfma_f32_16x16x32_bf16(al[i], bh, acc[i][j], 0, 0, 0);
            }
            __builtin_amdgcn_s_setprio(0);
            if (j == 3 && t < 15) {
                // fold tile-(t+1)-ready wait into phase-3 exit (loads had
                // phases 2-3 to land; per-wave drain then shared barrier)
                asm volatile("s_waitcnt vmcnt(0)" ::: "memory");
                __builtin_amdgcn_sched_barrier(0);
            }
            __builtin_amdgcn_s_barrier();               // phase exit
        }
    }

    if (EPI == 1) {
        // bias + plain [row, col]
#pragma unroll
        for (int j = 0; j < 4; ++j) {
            int col = n0 + wc + 16 * j + m;
            float bv = bp[col];
#pragma unroll
            for (int i = 0; i < 8; ++i) {
                size_t rbase = (size_t)(l0 + wr + 16 * i + quad * 4) * ND + col;
#pragma unroll
                for (int r = 0; r < 4; ++r)
                    Out[rbase + (size_t)r * ND] = acc[i][j][r] + bv;
            }
        }
    } else {
        // transposed write YT[b, n, l] via LDS, 32-col chunks (8 chunks)
#pragma unroll
        for (int c = 0; c < 8; ++c) {
            __syncthreads();
            if ((wc >> 6) == (c >> 1)) {
                int jb = (c & 1) * 2;
#pragma unroll
                for (int jj = 0; jj < 2; ++jj) {
                    int j = jb + jj;
                    int cl = 16 * jj + m;
#pragma unroll
                    for (int i = 0; i < 8; ++i)
#pragma unroll
                        for (int r = 0; r < 4; ++r)
                            sm.t[cl * 257 + wr + 16 * i + quad * 4 + r] = acc[i][j][r];
                }
            }
            __syncthreads();
#pragma unroll
            for (int it = 0; it < 16; ++it) {
                int idx = it * 512 + tid;
                int cl = idx >> 8;
                int row = idx & 255;
                int rg = l0 + row;
                Out[((size_t)((rg >> 12) * ND + n0 + c * 32 + cl)) * NL + (rg & 4095)] =
                    sm.t[cl * 257 + row];
            }
        }
    }
}

// ---------------------------------------------------------------------------
// 16-point in-register DFT (natural in/out). DIR=+1 fwd (e^{-i}), -1 inverse.
// ---------------------------------------------------------------------------
template <int DIR>
__device__ __forceinline__ void fft16(float2* v) {
    const float ct[8] = {1.f, 0.923879533f, 0.707106781f, 0.382683432f,
                         0.f, -0.382683432f, -0.707106781f, -0.923879533f};
    const float st[8] = {0.f, 0.382683432f, 0.707106781f, 0.923879533f,
                         1.f, 0.923879533f, 0.707106781f, 0.382683432f};
    const int br[16] = {0, 8, 4, 12, 2, 10, 6, 14, 1, 9, 5, 13, 3, 11, 7, 15};
    float2 a[16];
#pragma unroll
    for (int i = 0; i < 16; ++i) a[i] = v[br[i]];
#pragma unroll
    for (int s = 1; s <= 4; ++s) {
        const int L = 1 << s, h = L >> 1;
#pragma unroll
        for (int g = 0; g < 16; g += L)
#pragma unroll
            for (int p = 0; p < h; ++p) {
                int k = p << (4 - s);
                float wr = ct[k];
                float wi = (DIR > 0) ? -st[k] : st[k];
                int i1 = g + p, i2 = i1 + h;
                float tr = wr * a[i2].x - wi * a[i2].y;
                float ti = wr * a[i2].y + wi * a[i2].x;
                a[i2].x = a[i1].x - tr; a[i2].y = a[i1].y - ti;
                a[i1].x += tr;          a[i1].y += ti;
            }
    }
#pragma unroll
    for (int i = 0; i < 16; ++i) v[i] = a[i];
}

__device__ __forceinline__ float2 cmul(float2 a, float2 b) {
    return make_float2(a.x * b.x - a.y * b.y, a.x * b.y + a.y * b.x);
}
#define PADI(i) ((i) + ((i) >> 4))

// ---------------------------------------------------------------------------
// Forward: per (batch, group of 8 channels): z = x + i*y, 4096-pt Stockham
// radix-16 FFT (3 stages), accumulate cross-spectrum
// X_c(f)*conj(Y_c(f)) = Im(Z_f*Z_{-f})/2 + i*(|Z_f|^2-|Z_{-f}|^2)/4
// into partial[b, g, f].
// ---------------------------------------------------------------------------
__global__ __launch_bounds__(256) void k_fft_fwd(const float* __restrict__ XT,
                                                 const float* __restrict__ YT,
                                                 float2* __restrict__ partial) {
    __shared__ float2 data[4352];   // 4096 + pad
    const int t = threadIdx.x;
    const int b = blockIdx.x >> 6;
    const int g = blockIdx.x & 63;

    float sv, cv;
    sincosf(-6.283185307179586f * (float)(t & 15) / 256.0f, &sv, &cv);
    const float2 w2 = make_float2(cv, sv);
    sincosf(-6.283185307179586f * (float)t / 4096.0f, &sv, &cv);
    const float2 w3 = make_float2(cv, sv);

    float2 acc[16];
#pragma unroll
    for (int r = 0; r < 16; ++r) acc[r] = make_float2(0.f, 0.f);

    for (int ch = 0; ch < 8; ++ch) {
        int c = g * 8 + ch;
        const float* xr = XT + ((size_t)b * ND + c) * NL;
        const float* yr = YT + ((size_t)b * ND + c) * NL;
        float2 v[16];
        // stage 1 (Ns=1): read natural, fft16, write idx 16t+m
#pragma unroll
        for (int mm = 0; mm < 16; ++mm)
            v[mm] = make_float2(xr[t + 256 * mm], yr[t + 256 * mm]);
        fft16<1>(v);
        __syncthreads();   // prior channel's pair-reads done
#pragma unroll
        for (int mm = 0; mm < 16; ++mm) data[PADI(16 * t + mm)] = v[mm];
        __syncthreads();
        // stage 2 (Ns=16)
#pragma unroll
        for (int mm = 0; mm < 16; ++mm) v[mm] = data[PADI(t + 256 * mm)];
        {
            float2 wm = make_float2(1.f, 0.f);
#pragma unroll
            for (int mm = 1; mm < 16; ++mm) { wm = cmul(wm, w2); v[mm] = cmul(v[mm], wm); }
        }
        fft16<1>(v);
        __syncthreads();
        {
            int base = (t >> 4) * 256 + (t & 15);
#pragma unroll
            for (int mm = 0; mm < 16; ++mm) data[PADI(base + 16 * mm)] = v[mm];
        }
        __syncthreads();
        // stage 3 (Ns=256) -> natural-order Z in registers
#pragma unroll
        for (int mm = 0; mm < 16; ++mm) v[mm] = data[PADI(t + 256 * mm)];
        {
            float2 wm = make_float2(1.f, 0.f);
#pragma unroll
            for (int mm = 1; mm < 16; ++mm) { wm = cmul(wm, w3); v[mm] = cmul(v[mm], wm); }
        }
        fft16<1>(v);
        __syncthreads();
#pragma unroll
        for (int mm = 0; mm < 16; ++mm) data[PADI(t + 256 * mm)] = v[mm];
        __syncthreads();
        // cross-spectrum accumulate
#pragma unroll
        for (int mm = 0; mm < 16; ++mm) {
            int f = t + 256 * mm;
            float2 A = v[mm];
            float2 Bz = data[PADI((4096 - f) & 4095)];
            acc[mm].x += 0.5f * (A.x * Bz.y + A.y * Bz.x);
            acc[mm].y += 0.25f * ((A.x * A.x + A.y * A.y) - (Bz.x * Bz.x + Bz.y * Bz.y));
        }
    }
    float2* out = partial + ((size_t)b * 64 + g) * 4096;
#pragma unroll
    for (int mm = 0; mm < 16; ++mm) out[256 * mm + t] = acc[mm];
}

// Reduce 64 partials -> Cf[b][f]
__global__ __launch_bounds__(256) void k_reduce(const float2* __restrict__ partial,
                                                float2* __restrict__ Cf) {
    int b = blockIdx.x >> 4;
    int f = (blockIdx.x & 15) * 256 + threadIdx.x;
    float2 s = make_float2(0.f, 0.f);
    for (int g = 0; g < 64; ++g) {
        float2 v = partial[((size_t)(b * 64 + g)) * 4096 + f];
        s.x += v.x; s.y += v.y;
    }
    Cf[(size_t)b * 4096 + f] = s;
}

// ---------------------------------------------------------------------------
// Fused: inverse 4096-pt Stockham on Cf -> mean_corr (in LDS) -> top-8 +
// softmax per batch. Saves a kernel launch + the mc global round-trip.
// ---------------------------------------------------------------------------
__global__ __launch_bounds__(256) void k_ifft_topk(const float2* __restrict__ Cf,
                                                   float* __restrict__ wts,
                                                   int* __restrict__ dly) {
    __shared__ float2 data[4352];
    __shared__ float vals[4096];
    __shared__ float rv[256];
    __shared__ int ri[256];
    __shared__ float tv[NK];
    __shared__ int tix[NK];
    const int t = threadIdx.x;
    const int b = blockIdx.x;
    float sv, cv;
    sincosf(6.283185307179586f * (float)(t & 15) / 256.0f, &sv, &cv);
    const float2 w2 = make_float2(cv, sv);
    sincosf(6.283185307179586f * (float)t / 4096.0f, &sv, &cv);
    const float2 w3 = make_float2(cv, sv);

    float2 v[16];
#pragma unroll
    for (int mm = 0; mm < 16; ++mm) v[mm] = Cf[(size_t)b * 4096 + t + 256 * mm];
    fft16<-1>(v);
#pragma unroll
    for (int mm = 0; mm < 16; ++mm) data[PADI(16 * t + mm)] = v[mm];
    __syncthreads();
#pragma unroll
    for (int mm = 0; mm < 16; ++mm) v[mm] = data[PADI(t + 256 * mm)];
    {
        float2 wm = make_float2(1.f, 0.f);
#pragma unroll
        for (int mm = 1; mm < 16; ++mm) { wm = cmul(wm, w2); v[mm] = cmul(v[mm], wm); }
    }
    fft16<-1>(v);
    __syncthreads();
    {
        int base = (t >> 4) * 256 + (t & 15);
#pragma unroll
        for (int mm = 0; mm < 16; ++mm) data[PADI(base + 16 * mm)] = v[mm];
    }
    __syncthreads();
#pragma unroll
    for (int mm = 0; mm < 16; ++mm) v[mm] = data[PADI(t + 256 * mm)];
    {
        float2 wm = make_float2(1.f, 0.f);
#pragma unroll
        for (int mm = 1; mm < 16; ++mm) { wm = cmul(wm, w3); v[mm] = cmul(v[mm], wm); }
    }
    fft16<-1>(v);
    const float scale = 1.0f / (4096.0f * 512.0f);
#pragma unroll
    for (int mm = 0; mm < 16; ++mm)
        vals[t + 256 * mm] = v[mm].x * scale;
    __syncthreads();

    // top-8 + softmax
    for (int it = 0; it < NK; ++it) {
        float bv = -3.0e38f;
        int bi = 0;
        for (int tt = t; tt < 4096; tt += 256) {
            float vv = vals[tt];
            if (vv > bv) { bv = vv; bi = tt; }
        }
        rv[t] = bv;
        ri[t] = bi;
        __syncthreads();
        for (int off = 128; off > 0; off >>= 1) {
            if (t < off) {
                if (rv[t + off] > rv[t]) {
                    rv[t] = rv[t + off];
                    ri[t] = ri[t + off];
                }
            }
            __syncthreads();
        }
        if (t == 0) {
            tv[it] = rv[0];
            tix[it] = ri[0];
            vals[ri[0]] = -3.0e38f;
        }
        __syncthreads();
    }
    if (t == 0) {
        float mx = tv[0];
        float e[NK], s = 0.f;
        for (int i = 0; i < NK; ++i) { e[i] = expf(tv[i] - mx); s += e[i]; }
        for (int i = 0; i < NK; ++i) {
            wts[b * NK + i] = e[i] / s;
            dly[b * NK + i] = tix[i];
        }
    }
}

// ---------------------------------------------------------------------------
// Xagg[b,l,:] = sum_i w[b,i] * X[b,(l+d_i)%L,:], written split bf16 hi|lo
// ---------------------------------------------------------------------------
__global__ __launch_bounds__(256) void k_gather(const float* __restrict__ X,
                                                const float* __restrict__ wts,
                                                const int* __restrict__ dly,
                                                ushort_t* __restrict__ Xaggs) {
    __shared__ float sw[NK];
    __shared__ int sd[NK];
    int gid = blockIdx.x * 256 + threadIdx.x;
    int b = gid >> 19;
    int rem = gid & 524287;
    int l = rem >> 7;
    int c4 = rem & 127;
    if (threadIdx.x < NK) {
        sw[threadIdx.x] = wts[b * NK + threadIdx.x];
        sd[threadIdx.x] = dly[b * NK + threadIdx.x];
    }
    __syncthreads();
    const float4* Xb = (const float4*)X + (size_t)b * 524288;
    float4 s = make_float4(0.f, 0.f, 0.f, 0.f);
#pragma unroll
    for (int i = 0; i < NK; ++i) {
        int ls = (l + sd[i]) & (NL - 1);
        float4 v = Xb[(size_t)ls * 128 + c4];
        float w = sw[i];
        s.x += w * v.x;
        s.y += w * v.y;
        s.z += w * v.z;
        s.w += w * v.w;
    }
    ushort4 hi, lo;
    hi.x = f2bf(s.x); lo.x = f2bf(s.x - bf2f(hi.x));
    hi.y = f2bf(s.y); lo.y = f2bf(s.y - bf2f(hi.y));
    hi.z = f2bf(s.z); lo.z = f2bf(s.z - bf2f(hi.z));
    hi.w = f2bf(s.w); lo.w = f2bf(s.w - bf2f(hi.w));
    ushort_t* rowp = Xaggs + (size_t)(b * NL + l) * 1024;
    *(ushort4*)(rowp + c4 * 4) = hi;
    *(ushort4*)(rowp + 512 + c4 * 4) = lo;
}

// ---------------------------------------------------------------------------
extern "C" void kernel_launch(void* const* d_in, const int* in_sizes, int n_in,
                              void* d_out, int out_size, void* d_ws, size_t ws_size,
                              hipStream_t stream) {
    (void)in_sizes; (void)n_in; (void)out_size; (void)ws_size;
    const float* X  = (const float*)d_in[0];
    const float* Wq = (const float*)d_in[1];
    const float* Wk = (const float*)d_in[3];
    const float* Wv = (const float*)d_in[5];
    const float* bv = (const float*)d_in[6];
    const float* Wo = (const float*)d_in[7];
    const float* bo = (const float*)d_in[8];
    float* Out = (float*)d_out;

    char* ws = (char*)d_ws;
    const size_t MB = 1024 * 1024;
    // misc [0,5) MiB
    float*    M     = (float*)(ws + 0 * MB);             // 1 MB
    float*    Wov   = (float*)(ws + 1 * MB);             // 1 MB
    ushort_t* BsM   = (ushort_t*)(ws + 2 * MB);          // 1 MB
    ushort_t* BsW   = (ushort_t*)(ws + 3 * MB);          // 1 MB
    float*    bp    = (float*)(ws + 4 * MB);             // 2 KB
    float*    wts   = (float*)(ws + 4 * MB + 0x40000);   // 256 B
    int*      dly   = (int*)(ws + 4 * MB + 0x41000);     // 256 B
    float2*   Cf    = (float2*)(ws + 4 * MB + 0x80000);  // 256 KB
    // partial [5,21) MiB (16 MiB exact)
    float2*   partial = (float2*)(ws + 5 * MB);
    // R0 [21,85): Xs (split X) -> XT (fp32 transpose) -> (unused)
    ushort_t* Xs    = (ushort_t*)(ws + 21 * MB);
    float*    XT    = (float*)(ws + 21 * MB);
    // R1 [85,149): YT -> Xaggs (YT dead after fft_fwd)
    float*    YT    = (float*)(ws + 85 * MB);
    ushort_t* Xaggs = (ushort_t*)(ws + 85 * MB);

    // 1) weight prep: M = Wq^T Wk ; Wov = Wo @ Wv ; bp ; bf16 splits
    k_smallgemm<<<dim3(32, 32), dim3(16, 16), 0, stream>>>(Wq, Wk, M, ND, 1, ND, 1);
    k_smallgemm<<<dim3(32, 32), dim3(16, 16), 0, stream>>>(Wo, Wv, Wov, 1, ND, ND, 1);
    k_biasprep<<<1, 512, 0, stream>>>(Wo, bv, bo, bp);
    k_split<<<256, 256, 0, stream>>>(M, BsM);
    k_split<<<256, 256, 0, stream>>>(Wov, BsW);

    // 2) Xs = split(X);  YT = (X @ M^T)^T  (MFMA, 256^2, fine-phase schedule)
    k_split<<<16384, 256, 0, stream>>>(X, Xs);
    k_gemm_split<0><<<dim3(128, 2), 512, 0, stream>>>(Xs, BsM, nullptr, YT);

    // 3) XT = transpose(X)  (overwrites Xs region - Xs dead after GEMM1)
    k_transpose<<<dim3(128, 16, NB), dim3(32, 8), 0, stream>>>(X, XT);

    // 4) packed Stockham FFTs + channel-summed cross-spectrum; reduce;
    //    fused IFFT + top-8 + softmax
    k_fft_fwd<<<512, 256, 0, stream>>>(XT, YT, partial);
    k_reduce<<<128, 256, 0, stream>>>(partial, Cf);
    k_ifft_topk<<<NB, 256, 0, stream>>>(Cf, wts, dly);

    // 6) weighted circular gather, split-bf16 output (YT region, dead)
    k_gather<<<16384, 256, 0, stream>>>(X, wts, dly, Xaggs);

    // 7) Out = Xagg @ Wov^T + bp  (MFMA, 256^2, fine-phase schedule)
    k_gemm_split<1><<<dim3(128, 2), 512, 0, stream>>>(Xaggs, BsW, bp, Out);
}

// Round 10
// 542.114 us; speedup vs baseline: 1.1034x; 1.0593x over previous
//
#include <hip/hip_runtime.h>
#include <math.h>

// Problem constants (B=8, L=4096, D=512, H=8, top_k = int(log(4096)) = 8)
#define NB 8
#define NL 4096
#define ND 512
#define NK 8

typedef unsigned short ushort_t;
typedef __bf16 bf16x8 __attribute__((ext_vector_type(8)));
typedef float f32x4 __attribute__((ext_vector_type(4)));

__device__ __forceinline__ unsigned short f2bf(float x) {
    unsigned u = __builtin_bit_cast(unsigned, x);
    u += 0x7fff + ((u >> 16) & 1);   // round-to-nearest-even
    return (unsigned short)(u >> 16);
}
__device__ __forceinline__ float bf2f(unsigned short b) {
    unsigned u = ((unsigned)b) << 16;
    return __builtin_bit_cast(float, u);
}

// ---------------------------------------------------------------------------
// Fused weight-prep GEMM: C[i,j] = sum_k A[..]*B[..], written DIRECTLY as
// split bf16 hi|lo rows (no fp32 intermediate, no separate split launch).
// ---------------------------------------------------------------------------
__global__ void k_wprep(const float* __restrict__ A, const float* __restrict__ Bm,
                        ushort_t* __restrict__ dst, int sa_k, int sa_i, int sb_k, int sb_j) {
    int i = blockIdx.y * 16 + threadIdx.y;
    int j = blockIdx.x * 16 + threadIdx.x;
    float acc = 0.f;
    for (int k = 0; k < ND; ++k)
        acc += A[k * sa_k + i * sa_i] * Bm[k * sb_k + j * sb_j];
    unsigned short hi = f2bf(acc);
    unsigned short lo = f2bf(acc - bf2f(hi));
    dst[(size_t)i * 1024 + j] = hi;
    dst[(size_t)i * 1024 + 512 + j] = lo;
}

// bp[row] = bo[row] + sum_c Wo[row,c]*bv[c]  — one wave per row, shfl reduce.
// grid 128 blocks x 256 thr (4 waves): 512 rows.
__global__ __launch_bounds__(256) void k_biasprep(const float* __restrict__ Wo,
                                                  const float* __restrict__ bv,
                                                  const float* __restrict__ bo,
                                                  float* __restrict__ bp) {
    int wave = threadIdx.x >> 6, lane = threadIdx.x & 63;
    int row = blockIdx.x * 4 + wave;
    float s = 0.f;
#pragma unroll
    for (int c = lane; c < ND; c += 64) s += Wo[row * ND + c] * bv[c];
#pragma unroll
    for (int off = 32; off > 0; off >>= 1) s += __shfl_down(s, off, 64);
    if (lane == 0) bp[row] = bo[row] + s;
}

// Split fp32 rows into [row][0:512]=hi bf16, [row][512:1024]=lo bf16.
// grid = rows/2 blocks of 256 threads (each thread: 4 elements).
__global__ __launch_bounds__(256) void k_split(const float* __restrict__ src,
                                               ushort_t* __restrict__ dst) {
    int gid = blockIdx.x * 256 + threadIdx.x;
    int row = gid >> 7;
    int kc = (gid & 127) * 4;
    float4 v = *(const float4*)(src + (size_t)row * ND + kc);
    ushort4 hi, lo;
    hi.x = f2bf(v.x); lo.x = f2bf(v.x - bf2f(hi.x));
    hi.y = f2bf(v.y); lo.y = f2bf(v.y - bf2f(hi.y));
    hi.z = f2bf(v.z); lo.z = f2bf(v.z - bf2f(hi.z));
    hi.w = f2bf(v.w); lo.w = f2bf(v.w - bf2f(hi.w));
    *(ushort4*)(dst + (size_t)row * 1024 + kc) = hi;
    *(ushort4*)(dst + (size_t)row * 1024 + 512 + kc) = lo;
}

// ---------------------------------------------------------------------------
// Transpose X[b,l,c] -> XT[b,c,l]   (32x32 LDS tiles)
// ---------------------------------------------------------------------------
__global__ __launch_bounds__(256) void k_transpose(const float* __restrict__ X,
                                                   float* __restrict__ XT) {
    __shared__ float t[32][33];
    int b  = blockIdx.z;
    int l0 = blockIdx.x * 32;
    int c0 = blockIdx.y * 32;
    const float* Xb = X + (size_t)b * NL * ND;
    float* XTb = XT + (size_t)b * ND * NL;
    int tx = threadIdx.x, ty = threadIdx.y;  // 32 x 8
#pragma unroll
    for (int j = 0; j < 4; ++j)
        t[ty + j * 8][tx] = Xb[(size_t)(l0 + ty + j * 8) * ND + c0 + tx];
    __syncthreads();
#pragma unroll
    for (int j = 0; j < 4; ++j)
        XTb[(size_t)(c0 + ty + j * 8) * NL + l0 + tx] = t[tx][ty + j * 8];
}

// ---------------------------------------------------------------------------
// Split-bf16 MFMA GEMM:  C[r,n] = sum_k A[r,k] * Brow[n,k]
// A, B both pre-split bf16 [rows][1024] = hi(512) | lo(512).
// R8 schedule kept (measured 87us, best of R1-R8): fine-phase, 4 phases per
// K-iter (one per B col-group j): {ds_read (phase0 also A-frags) | issue 4
// stage loads (phases 0-1) -> s_barrier -> lgkmcnt(0)+sched_barrier ->
// setprio(1) -> 24 MFMA -> setprio(0) -> s_barrier}. 1-deep prefetch,
// WAR-safe: tile t+1 stages into buf c^1 (fully read in iter t-1).
// Staging layout (R7): coalesced source, chunk q -> row r=q>>2, chunk
// c=(q&3)^((r>>1)&3); fragment read off = row*32 + (quad^((row>>1)&3))*8
// (<=2-way bank alias, free). 256x256 tile, 8 waves (2Mx4N), BK=32, 128KB
// LDS, 1 block/CU, grid=256. 3-term split: Ah*Bh + Ah*Bl + Al*Bh.
// XCD-chunked tile remap keeps A/B panels L2-resident per XCD.
// EPI=0: write transposed YT[b,n,l]; EPI=1: bias + plain [r,n].
// ---------------------------------------------------------------------------
template <int EPI>
__global__ __launch_bounds__(512, 2) void k_gemm_split(const ushort_t* __restrict__ As,
                                                       const ushort_t* __restrict__ Bs,
                                                       const float* __restrict__ bp,
                                                       float* __restrict__ Out) {
    struct Buf { ushort_t ahi[256 * 32]; ushort_t alo[256 * 32];
                 ushort_t bhi[256 * 32]; ushort_t blo[256 * 32]; };   // 64 KB
    __shared__ union USm {
        Buf s[2];                                                      // 128 KB
        float t[32 * 257];                                             // epilogue transpose
    } sm;
    const int tid = threadIdx.x;
    // hw linear block id -> XCD-chunked bijection (256 = 8 XCDs * 32)
    const int flat = blockIdx.x + (blockIdx.y << 7);   // gridDim.x = 128
    const int wswz = ((flat & 7) << 5) + (flat >> 3);
    const int l0 = (wswz >> 1) * 256;   // 128 l-tiles
    const int n0 = (wswz & 1) * 256;    // 2 n-tiles, adjacent per A-panel
    const int lane = tid & 63;
    const int w = tid >> 6;             // 0..7
    const int wr = (w & 1) * 128;       // wave row-group: 0 / 128
    const int wc = (w >> 1) * 64;       // wave col-group: 0/64/128/192
    const int m = lane & 15;
    const int quad = lane >> 4;

    f32x4 acc[8][4];
#pragma unroll
    for (int i = 0; i < 8; ++i)
#pragma unroll
        for (int j = 0; j < 4; ++j) acc[i][j] = (f32x4){0.f, 0.f, 0.f, 0.f};

    // Stage one half-tile (4 gload_lds per thread). Coalesced source:
    // chunk q: row r=q>>2, source chunk c=(q&3)^((r>>1)&3); LDS dest linear.
    auto STAGE_HALF = [&](int bf, int k0, int v) {
        int q = v * 512 + tid;
        int r = q >> 2;
        int c = (q & 3) ^ ((r >> 1) & 3);
        const ushort_t* asrc = As + (size_t)(l0 + r) * 1024 + k0 + c * 8;
        __builtin_amdgcn_global_load_lds(
            (const __attribute__((address_space(1))) unsigned int*)asrc,
            (__attribute__((address_space(3))) unsigned int*)&sm.s[bf].ahi[q * 8], 16, 0, 0);
        __builtin_amdgcn_global_load_lds(
            (const __attribute__((address_space(1))) unsigned int*)(asrc + 512),
            (__attribute__((address_space(3))) unsigned int*)&sm.s[bf].alo[q * 8], 16, 0, 0);
        const ushort_t* bsrc = Bs + (size_t)(n0 + r) * 1024 + k0 + c * 8;
        __builtin_amdgcn_global_load_lds(
            (const __attribute__((address_space(1))) unsigned int*)bsrc,
            (__attribute__((address_space(3))) unsigned int*)&sm.s[bf].bhi[q * 8], 16, 0, 0);
        __builtin_amdgcn_global_load_lds(
            (const __attribute__((address_space(1))) unsigned int*)(bsrc + 512),
            (__attribute__((address_space(3))) unsigned int*)&sm.s[bf].blo[q * 8], 16, 0, 0);
    };

    // prologue: stage tile 0 (both halves); drain; barrier
    STAGE_HALF(0, 0, 0);
    STAGE_HALF(0, 0, 1);
    asm volatile("s_waitcnt vmcnt(0)" ::: "memory");
    __builtin_amdgcn_sched_barrier(0);
    __builtin_amdgcn_s_barrier();

    for (int t = 0; t < 16; ++t) {
        const int c = t & 1;
        bf16x8 ah[8], al[8];
#pragma unroll
        for (int i = 0; i < 8; ++i) {
            int row = wr + 16 * i + m;
            int off = row * 32 + ((quad ^ ((row >> 1) & 3)) * 8);
            ah[i] = *(const bf16x8*)&sm.s[c].ahi[off];
            al[i] = *(const bf16x8*)&sm.s[c].alo[off];
        }
#pragma unroll
        for (int j = 0; j < 4; ++j) {
            int row = wc + 16 * j + m;
            int off = row * 32 + ((quad ^ ((row >> 1) & 3)) * 8);
            bf16x8 bh = *(const bf16x8*)&sm.s[c].bhi[off];
            bf16x8 bl = *(const bf16x8*)&sm.s[c].blo[off];
            // fine interleave: issue next-tile stage loads during phases 0,1
            if (t < 15 && j < 2) STAGE_HALF(c ^ 1, (t + 1) * 32, j);
            __builtin_amdgcn_s_barrier();               // phase entry align
            asm volatile("s_waitcnt lgkmcnt(0)" ::: "memory");
            __builtin_amdgcn_sched_barrier(0);
            __builtin_amdgcn_s_setprio(1);
#pragma unroll
            for (int i = 0; i < 8; ++i) {
                acc[i][j] = __builtin_amdgcn_mfma_f32_16x16x32_bf16(ah[i], bh, acc[i][j], 0, 0, 0);
                acc[i][j] = __builtin_amdgcn_mfma_f32_16x16x32_bf16(ah[i], bl, acc[i][j], 0, 0, 0);
                acc[i][j] = __builtin_amdgcn_mfma_f32_16x16x32_bf16(al[i], bh, acc[i][j], 0, 0, 0);
            }
            __builtin_amdgcn_s_setprio(0);
            if (j == 3 && t < 15) {
                // fold tile-(t+1)-ready wait into phase-3 exit (loads had
                // phases 2-3 to land; per-wave drain then shared barrier)
                asm volatile("s_waitcnt vmcnt(0)" ::: "memory");
                __builtin_amdgcn_sched_barrier(0);
            }
            __builtin_amdgcn_s_barrier();               // phase exit
        }
    }

    if (EPI == 1) {
        // bias + plain [row, col]
#pragma unroll
        for (int j = 0; j < 4; ++j) {
            int col = n0 + wc + 16 * j + m;
            float bv = bp[col];
#pragma unroll
            for (int i = 0; i < 8; ++i) {
                size_t rbase = (size_t)(l0 + wr + 16 * i + quad * 4) * ND + col;
#pragma unroll
                for (int r = 0; r < 4; ++r)
                    Out[rbase + (size_t)r * ND] = acc[i][j][r] + bv;
            }
        }
    } else {
        // transposed write YT[b, n, l] via LDS, 32-col chunks (8 chunks)
#pragma unroll
        for (int c = 0; c < 8; ++c) {
            __syncthreads();
            if ((wc >> 6) == (c >> 1)) {
                int jb = (c & 1) * 2;
#pragma unroll
                for (int jj = 0; jj < 2; ++jj) {
                    int j = jb + jj;
                    int cl = 16 * jj + m;
#pragma unroll
                    for (int i = 0; i < 8; ++i)
#pragma unroll
                        for (int r = 0; r < 4; ++r)
                            sm.t[cl * 257 + wr + 16 * i + quad * 4 + r] = acc[i][j][r];
                }
            }
            __syncthreads();
#pragma unroll
            for (int it = 0; it < 16; ++it) {
                int idx = it * 512 + tid;
                int cl = idx >> 8;
                int row = idx & 255;
                int rg = l0 + row;
                Out[((size_t)((rg >> 12) * ND + n0 + c * 32 + cl)) * NL + (rg & 4095)] =
                    sm.t[cl * 257 + row];
            }
        }
    }
}

// ---------------------------------------------------------------------------
// 16-point in-register DFT (natural in/out). DIR=+1 fwd (e^{-i}), -1 inverse.
// ---------------------------------------------------------------------------
template <int DIR>
__device__ __forceinline__ void fft16(float2* v) {
    const float ct[8] = {1.f, 0.923879533f, 0.707106781f, 0.382683432f,
                         0.f, -0.382683432f, -0.707106781f, -0.923879533f};
    const float st[8] = {0.f, 0.382683432f, 0.707106781f, 0.923879533f,
                         1.f, 0.923879533f, 0.707106781f, 0.382683432f};
    const int br[16] = {0, 8, 4, 12, 2, 10, 6, 14, 1, 9, 5, 13, 3, 11, 7, 15};
    float2 a[16];
#pragma unroll
    for (int i = 0; i < 16; ++i) a[i] = v[br[i]];
#pragma unroll
    for (int s = 1; s <= 4; ++s) {
        const int L = 1 << s, h = L >> 1;
#pragma unroll
        for (int g = 0; g < 16; g += L)
#pragma unroll
            for (int p = 0; p < h; ++p) {
                int k = p << (4 - s);
                float wr = ct[k];
                float wi = (DIR > 0) ? -st[k] : st[k];
                int i1 = g + p, i2 = i1 + h;
                float tr = wr * a[i2].x - wi * a[i2].y;
                float ti = wr * a[i2].y + wi * a[i2].x;
                a[i2].x = a[i1].x - tr; a[i2].y = a[i1].y - ti;
                a[i1].x += tr;          a[i1].y += ti;
            }
    }
#pragma unroll
    for (int i = 0; i < 16; ++i) v[i] = a[i];
}

__device__ __forceinline__ float2 cmul(float2 a, float2 b) {
    return make_float2(a.x * b.x - a.y * b.y, a.x * b.y + a.y * b.x);
}
#define PADI(i) ((i) + ((i) >> 4))

// ---------------------------------------------------------------------------
// Forward: per (batch, group of 8 channels): z = x + i*y, 4096-pt Stockham
// radix-16 FFT (3 stages), accumulate cross-spectrum
// X_c(f)*conj(Y_c(f)) = Im(Z_f*Z_{-f})/2 + i*(|Z_f|^2-|Z_{-f}|^2)/4
// into partial[b, g, f].
// ---------------------------------------------------------------------------
__global__ __launch_bounds__(256) void k_fft_fwd(const float* __restrict__ XT,
                                                 const float* __restrict__ YT,
                                                 float2* __restrict__ partial) {
    __shared__ float2 data[4352];   // 4096 + pad
    const int t = threadIdx.x;
    const int b = blockIdx.x >> 6;
    const int g = blockIdx.x & 63;

    float sv, cv;
    sincosf(-6.283185307179586f * (float)(t & 15) / 256.0f, &sv, &cv);
    const float2 w2 = make_float2(cv, sv);
    sincosf(-6.283185307179586f * (float)t / 4096.0f, &sv, &cv);
    const float2 w3 = make_float2(cv, sv);

    float2 acc[16];
#pragma unroll
    for (int r = 0; r < 16; ++r) acc[r] = make_float2(0.f, 0.f);

    for (int ch = 0; ch < 8; ++ch) {
        int c = g * 8 + ch;
        const float* xr = XT + ((size_t)b * ND + c) * NL;
        const float* yr = YT + ((size_t)b * ND + c) * NL;
        float2 v[16];
        // stage 1 (Ns=1): read natural, fft16, write idx 16t+m
#pragma unroll
        for (int mm = 0; mm < 16; ++mm)
            v[mm] = make_float2(xr[t + 256 * mm], yr[t + 256 * mm]);
        fft16<1>(v);
        __syncthreads();   // prior channel's pair-reads done
#pragma unroll
        for (int mm = 0; mm < 16; ++mm) data[PADI(16 * t + mm)] = v[mm];
        __syncthreads();
        // stage 2 (Ns=16)
#pragma unroll
        for (int mm = 0; mm < 16; ++mm) v[mm] = data[PADI(t + 256 * mm)];
        {
            float2 wm = make_float2(1.f, 0.f);
#pragma unroll
            for (int mm = 1; mm < 16; ++mm) { wm = cmul(wm, w2); v[mm] = cmul(v[mm], wm); }
        }
        fft16<1>(v);
        __syncthreads();
        {
            int base = (t >> 4) * 256 + (t & 15);
#pragma unroll
            for (int mm = 0; mm < 16; ++mm) data[PADI(base + 16 * mm)] = v[mm];
        }
        __syncthreads();
        // stage 3 (Ns=256) -> natural-order Z in registers
#pragma unroll
        for (int mm = 0; mm < 16; ++mm) v[mm] = data[PADI(t + 256 * mm)];
        {
            float2 wm = make_float2(1.f, 0.f);
#pragma unroll
            for (int mm = 1; mm < 16; ++mm) { wm = cmul(wm, w3); v[mm] = cmul(v[mm], wm); }
        }
        fft16<1>(v);
        __syncthreads();
#pragma unroll
        for (int mm = 0; mm < 16; ++mm) data[PADI(t + 256 * mm)] = v[mm];
        __syncthreads();
        // cross-spectrum accumulate
#pragma unroll
        for (int mm = 0; mm < 16; ++mm) {
            int f = t + 256 * mm;
            float2 A = v[mm];
            float2 Bz = data[PADI((4096 - f) & 4095)];
            acc[mm].x += 0.5f * (A.x * Bz.y + A.y * Bz.x);
            acc[mm].y += 0.25f * ((A.x * A.x + A.y * A.y) - (Bz.x * Bz.x + Bz.y * Bz.y));
        }
    }
    float2* out = partial + ((size_t)b * 64 + g) * 4096;
#pragma unroll
    for (int mm = 0; mm < 16; ++mm) out[256 * mm + t] = acc[mm];
}

// Reduce 64 partials -> Cf[b][f]
__global__ __launch_bounds__(256) void k_reduce(const float2* __restrict__ partial,
                                                float2* __restrict__ Cf) {
    int b = blockIdx.x >> 4;
    int f = (blockIdx.x & 15) * 256 + threadIdx.x;
    float2 s = make_float2(0.f, 0.f);
    for (int g = 0; g < 64; ++g) {
        float2 v = partial[((size_t)(b * 64 + g)) * 4096 + f];
        s.x += v.x; s.y += v.y;
    }
    Cf[(size_t)b * 4096 + f] = s;
}

// ---------------------------------------------------------------------------
// Fused: inverse 4096-pt Stockham on Cf -> mean_corr (in LDS) -> top-8 +
// softmax per batch. R9: topk reduction via wave shfl argmax (2 barriers
// per top-k iteration instead of ~10 LDS-tree barriers).
// ---------------------------------------------------------------------------
__global__ __launch_bounds__(256) void k_ifft_topk(const float2* __restrict__ Cf,
                                                   float* __restrict__ wts,
                                                   int* __restrict__ dly) {
    __shared__ float2 data[4352];
    __shared__ float vals[4096];
    __shared__ float rv4[4];
    __shared__ int ri4[4];
    __shared__ float tv[NK];
    __shared__ int tix[NK];
    const int t = threadIdx.x;
    const int b = blockIdx.x;
    float sv, cv;
    sincosf(6.283185307179586f * (float)(t & 15) / 256.0f, &sv, &cv);
    const float2 w2 = make_float2(cv, sv);
    sincosf(6.283185307179586f * (float)t / 4096.0f, &sv, &cv);
    const float2 w3 = make_float2(cv, sv);

    float2 v[16];
#pragma unroll
    for (int mm = 0; mm < 16; ++mm) v[mm] = Cf[(size_t)b * 4096 + t + 256 * mm];
    fft16<-1>(v);
#pragma unroll
    for (int mm = 0; mm < 16; ++mm) data[PADI(16 * t + mm)] = v[mm];
    __syncthreads();
#pragma unroll
    for (int mm = 0; mm < 16; ++mm) v[mm] = data[PADI(t + 256 * mm)];
    {
        float2 wm = make_float2(1.f, 0.f);
#pragma unroll
        for (int mm = 1; mm < 16; ++mm) { wm = cmul(wm, w2); v[mm] = cmul(v[mm], wm); }
    }
    fft16<-1>(v);
    __syncthreads();
    {
        int base = (t >> 4) * 256 + (t & 15);
#pragma unroll
        for (int mm = 0; mm < 16; ++mm) data[PADI(base + 16 * mm)] = v[mm];
    }
    __syncthreads();
#pragma unroll
    for (int mm = 0; mm < 16; ++mm) v[mm] = data[PADI(t + 256 * mm)];
    {
        float2 wm = make_float2(1.f, 0.f);
#pragma unroll
        for (int mm = 1; mm < 16; ++mm) { wm = cmul(wm, w3); v[mm] = cmul(v[mm], wm); }
    }
    fft16<-1>(v);
    const float scale = 1.0f / (4096.0f * 512.0f);
#pragma unroll
    for (int mm = 0; mm < 16; ++mm)
        vals[t + 256 * mm] = v[mm].x * scale;
    __syncthreads();

    // top-8 via per-thread scan + wave shfl argmax + 4-wave merge
    for (int it = 0; it < NK; ++it) {
        float bv = -3.0e38f;
        int bi = 0;
        for (int tt = t; tt < 4096; tt += 256) {
            float vv = vals[tt];
            if (vv > bv) { bv = vv; bi = tt; }
        }
#pragma unroll
        for (int off = 32; off > 0; off >>= 1) {
            float ov = __shfl_down(bv, off, 64);
            int   oi = __shfl_down(bi, off, 64);
            if (ov > bv) { bv = ov; bi = oi; }
        }
        if ((t & 63) == 0) { rv4[t >> 6] = bv; ri4[t >> 6] = bi; }
        __syncthreads();
        if (t == 0) {
            float m0 = rv4[0]; int i0 = ri4[0];
#pragma unroll
            for (int q = 1; q < 4; ++q)
                if (rv4[q] > m0) { m0 = rv4[q]; i0 = ri4[q]; }
            tv[it] = m0;
            tix[it] = i0;
            vals[i0] = -3.0e38f;
        }
        __syncthreads();
    }
    if (t == 0) {
        float mx = tv[0];
        float e[NK], s = 0.f;
        for (int i = 0; i < NK; ++i) { e[i] = expf(tv[i] - mx); s += e[i]; }
        for (int i = 0; i < NK; ++i) {
            wts[b * NK + i] = e[i] / s;
            dly[b * NK + i] = tix[i];
        }
    }
}

// ---------------------------------------------------------------------------
// Xagg[b,l,:] = sum_i w[b,i] * X[b,(l+d_i)%L,:], written split bf16 hi|lo
// ---------------------------------------------------------------------------
__global__ __launch_bounds__(256) void k_gather(const float* __restrict__ X,
                                                const float* __restrict__ wts,
                                                const int* __restrict__ dly,
                                                ushort_t* __restrict__ Xaggs) {
    __shared__ float sw[NK];
    __shared__ int sd[NK];
    int gid = blockIdx.x * 256 + threadIdx.x;
    int b = gid >> 19;
    int rem = gid & 524287;
    int l = rem >> 7;
    int c4 = rem & 127;
    if (threadIdx.x < NK) {
        sw[threadIdx.x] = wts[b * NK + threadIdx.x];
        sd[threadIdx.x] = dly[b * NK + threadIdx.x];
    }
    __syncthreads();
    const float4* Xb = (const float4*)X + (size_t)b * 524288;
    float4 s = make_float4(0.f, 0.f, 0.f, 0.f);
#pragma unroll
    for (int i = 0; i < NK; ++i) {
        int ls = (l + sd[i]) & (NL - 1);
        float4 v = Xb[(size_t)ls * 128 + c4];
        float w = sw[i];
        s.x += w * v.x;
        s.y += w * v.y;
        s.z += w * v.z;
        s.w += w * v.w;
    }
    ushort4 hi, lo;
    hi.x = f2bf(s.x); lo.x = f2bf(s.x - bf2f(hi.x));
    hi.y = f2bf(s.y); lo.y = f2bf(s.y - bf2f(hi.y));
    hi.z = f2bf(s.z); lo.z = f2bf(s.z - bf2f(hi.z));
    hi.w = f2bf(s.w); lo.w = f2bf(s.w - bf2f(hi.w));
    ushort_t* rowp = Xaggs + (size_t)(b * NL + l) * 1024;
    *(ushort4*)(rowp + c4 * 4) = hi;
    *(ushort4*)(rowp + 512 + c4 * 4) = lo;
}

// ---------------------------------------------------------------------------
extern "C" void kernel_launch(void* const* d_in, const int* in_sizes, int n_in,
                              void* d_out, int out_size, void* d_ws, size_t ws_size,
                              hipStream_t stream) {
    (void)in_sizes; (void)n_in; (void)out_size; (void)ws_size;
    const float* X  = (const float*)d_in[0];
    const float* Wq = (const float*)d_in[1];
    const float* Wk = (const float*)d_in[3];
    const float* Wv = (const float*)d_in[5];
    const float* bv = (const float*)d_in[6];
    const float* Wo = (const float*)d_in[7];
    const float* bo = (const float*)d_in[8];
    float* Out = (float*)d_out;

    char* ws = (char*)d_ws;
    const size_t MB = 1024 * 1024;
    // misc [0,5) MiB
    ushort_t* BsM   = (ushort_t*)(ws + 2 * MB);          // 1 MB
    ushort_t* BsW   = (ushort_t*)(ws + 3 * MB);          // 1 MB
    float*    bp    = (float*)(ws + 4 * MB);             // 2 KB
    float*    wts   = (float*)(ws + 4 * MB + 0x40000);   // 256 B
    int*      dly   = (int*)(ws + 4 * MB + 0x41000);     // 256 B
    float2*   Cf    = (float2*)(ws + 4 * MB + 0x80000);  // 256 KB
    // partial [5,21) MiB (16 MiB exact)
    float2*   partial = (float2*)(ws + 5 * MB);
    // R0 [21,85): Xs (split X) -> XT (fp32 transpose) -> (unused)
    ushort_t* Xs    = (ushort_t*)(ws + 21 * MB);
    float*    XT    = (float*)(ws + 21 * MB);
    // R1 [85,149): YT -> Xaggs (YT dead after fft_fwd)
    float*    YT    = (float*)(ws + 85 * MB);
    ushort_t* Xaggs = (ushort_t*)(ws + 85 * MB);

    // 1) weight prep (fused GEMM+split, no fp32 intermediates):
    //    BsM = split(Wq^T Wk) ; BsW = split(Wo @ Wv) ; bp (parallel matvec)
    k_wprep<<<dim3(32, 32), dim3(16, 16), 0, stream>>>(Wq, Wk, BsM, ND, 1, ND, 1);
    k_wprep<<<dim3(32, 32), dim3(16, 16), 0, stream>>>(Wo, Wv, BsW, 1, ND, ND, 1);
    k_biasprep<<<128, 256, 0, stream>>>(Wo, bv, bo, bp);

    // 2) Xs = split(X);  YT = (X @ M^T)^T  (MFMA, 256^2, fine-phase schedule)
    k_split<<<16384, 256, 0, stream>>>(X, Xs);
    k_gemm_split<0><<<dim3(128, 2), 512, 0, stream>>>(Xs, BsM, nullptr, YT);

    // 3) XT = transpose(X)  (overwrites Xs region - Xs dead after GEMM1)
    k_transpose<<<dim3(128, 16, NB), dim3(32, 8), 0, stream>>>(X, XT);

    // 4) packed Stockham FFTs + channel-summed cross-spectrum; reduce;
    //    fused IFFT + top-8 + softmax (shfl argmax)
    k_fft_fwd<<<512, 256, 0, stream>>>(XT, YT, partial);
    k_reduce<<<128, 256, 0, stream>>>(partial, Cf);
    k_ifft_topk<<<NB, 256, 0, stream>>>(Cf, wts, dly);

    // 6) weighted circular gather, split-bf16 output (YT region, dead)
    k_gather<<<16384, 256, 0, stream>>>(X, wts, dly, Xaggs);

    // 7) Out = Xagg @ Wov^T + bp  (MFMA, 256^2, fine-phase schedule)
    k_gemm_split<1><<<dim3(128, 2), 512, 0, stream>>>(Xaggs, BsW, bp, Out);
}